// Round 3
// baseline (583.519 us; speedup 1.0000x reference)
//
#include <hip/hip_runtime.h>
#include <hip/hip_bf16.h>

// Problem constants (B=4, H=W=56, C=256, 7x7 windows of 8x8, 8 heads x 32, top-4)
// Inputs fp32; d_out fp32 (reference output dtype). Intermediates bf16.
#define NPIX 12544   // B*56*56

__device__ __forceinline__ float bf2f(unsigned short u) {
    unsigned int x = ((unsigned int)u) << 16;
    float f; __builtin_memcpy(&f, &x, sizeof(f)); return f;
}

// ---------------------------------------------------------------------------
// K1: qkv GEMM  [12544,256](f32) x [256,768](f32) + bias -> bf16 [12544,768]
// ---------------------------------------------------------------------------
__global__ __launch_bounds__(256) void k_qkv_gemm(
    const float* __restrict__ X,
    const float* __restrict__ W,
    const float* __restrict__ bias,
    __hip_bfloat16* __restrict__ O)
{
    __shared__ float As[16][65];
    __shared__ float Bs[16][65];
    const int m0 = blockIdx.x * 64;
    const int n0 = blockIdx.y * 64;
    const int t  = threadIdx.x;
    const int tx = t & 15, ty = t >> 4;
    const int arow = t >> 2, akq = (t & 3) << 2;
    const int brow = t >> 4, bnq = (t & 15) << 2;
    float acc[4][4] = {};
    for (int kt = 0; kt < 256; kt += 16) {
        float4 av = *reinterpret_cast<const float4*>(&X[(m0 + arow) * 256 + kt + akq]);
        float4 bv = *reinterpret_cast<const float4*>(&W[(kt + brow) * 768 + n0 + bnq]);
        As[akq + 0][arow] = av.x;
        As[akq + 1][arow] = av.y;
        As[akq + 2][arow] = av.z;
        As[akq + 3][arow] = av.w;
        Bs[brow][bnq + 0] = bv.x;
        Bs[brow][bnq + 1] = bv.y;
        Bs[brow][bnq + 2] = bv.z;
        Bs[brow][bnq + 3] = bv.w;
        __syncthreads();
        #pragma unroll
        for (int kk = 0; kk < 16; kk++) {
            float a[4], b[4];
            #pragma unroll
            for (int i = 0; i < 4; i++) a[i] = As[kk][ty + 16 * i];
            #pragma unroll
            for (int j = 0; j < 4; j++) b[j] = Bs[kk][tx + 16 * j];
            #pragma unroll
            for (int i = 0; i < 4; i++)
                #pragma unroll
                for (int j = 0; j < 4; j++)
                    acc[i][j] += a[i] * b[j];
        }
        __syncthreads();
    }
    #pragma unroll
    for (int j = 0; j < 4; j++) {
        int n = n0 + tx + 16 * j;
        float bb = bias[n];
        #pragma unroll
        for (int i = 0; i < 4; i++) {
            int m = m0 + ty + 16 * i;
            O[m * 768 + n] = __float2bfloat16(acc[i][j] + bb);
        }
    }
}

// ---------------------------------------------------------------------------
// K2: per-window mean of x (fp32, exact routing path; mean commutes with matmul)
// ---------------------------------------------------------------------------
__global__ __launch_bounds__(256) void k_xmean(
    const float* __restrict__ X, float* __restrict__ xmean)
{
    const int bp = blockIdx.x;            // 0..195
    const int b = bp / 49, p = bp % 49;
    const int wi = p / 7, wj = p % 7;
    const int c = threadIdx.x;
    float s = 0.f;
    for (int pp = 0; pp < 64; pp++) {
        int y = wi * 8 + (pp >> 3), x = wj * 8 + (pp & 7);
        s += X[(((b * 56) + y) * 56 + x) * 256 + c];
    }
    xmean[bp * 256 + c] = s * (1.0f / 64.0f);
}

// ---------------------------------------------------------------------------
// K3: q_win / k_win = xmean @ Wqkv[:, 0:512] + bqkv[0:512]  (fp32)
// ---------------------------------------------------------------------------
__global__ __launch_bounds__(256) void k_winproj(
    const float* __restrict__ xmean,
    const float* __restrict__ W,
    const float* __restrict__ bias,
    float* __restrict__ qwin, float* __restrict__ kwin)
{
    __shared__ float xs[256];
    const int bp = blockIdx.x;
    const int c = threadIdx.x;
    xs[c] = xmean[bp * 256 + c];
    __syncthreads();
    float aq = 0.f, ak = 0.f;
    for (int k = 0; k < 256; k++) {
        float xv = xs[k];
        aq += xv * W[k * 768 + c];
        ak += xv * W[k * 768 + 256 + c];
    }
    qwin[bp * 256 + c] = aq + bias[c];
    kwin[bp * 256 + c] = ak + bias[256 + c];
}

// ---------------------------------------------------------------------------
// K4: routing logits (49x49 per batch) + top-4 (strict >, lowest-index ties)
// ---------------------------------------------------------------------------
__global__ __launch_bounds__(256) void k_route(
    const float* __restrict__ qwin, const float* __restrict__ kwin,
    int* __restrict__ ridx)
{
    __shared__ float lg[49][49];
    const int b = blockIdx.x;
    const int t = threadIdx.x;
    for (int idx = t; idx < 49 * 49; idx += 256) {
        int p = idx / 49, qq = idx % 49;
        const float* qp = &qwin[(b * 49 + p) * 256];
        const float* kp = &kwin[(b * 49 + qq) * 256];
        float a = 0.f;
        for (int c = 0; c < 256; c++) a += qp[c] * kp[c];
        lg[p][qq] = a * 0.0625f;   // scale = C^-0.5 applied to q_win
    }
    __syncthreads();
    if (t < 49) {
        unsigned long long used = 0ull;
        const int base = (b * 49 + t) * 4;
        for (int sel = 0; sel < 4; sel++) {
            float best = -1e30f; int bi = 0;
            for (int qq = 0; qq < 49; qq++) {
                if (!((used >> qq) & 1ull) && lg[t][qq] > best) { best = lg[t][qq]; bi = qq; }
            }
            used |= (1ull << bi);
            ridx[base + sel] = bi;
        }
    }
}

// ---------------------------------------------------------------------------
// K5: depthwise 5x5 LEPE conv on v channels (qkv[...,512:768]) + bias -> bf16
// ---------------------------------------------------------------------------
__global__ __launch_bounds__(256) void k_lepe(
    const __hip_bfloat16* __restrict__ QKV,
    const float* __restrict__ lw,   // [5][5][1][256] fp32
    const float* __restrict__ lb,   // [256] fp32
    __hip_bfloat16* __restrict__ Olepe)
{
    const int blk = blockIdx.x;              // 0..12543
    const int b = blk / 3136, rem = blk % 3136;
    const int y = rem / 56, x = rem % 56;
    const int c = threadIdx.x;
    float a = lb[c];
    #pragma unroll
    for (int ky = 0; ky < 5; ky++) {
        int yy = y + ky - 2;
        if (yy < 0 || yy >= 56) continue;
        #pragma unroll
        for (int kx = 0; kx < 5; kx++) {
            int xx = x + kx - 2;
            if (xx < 0 || xx >= 56) continue;
            a += __bfloat162float(QKV[(((b * 56) + yy) * 56 + xx) * 768 + 512 + c]) *
                 lw[(ky * 5 + kx) * 256 + c];
        }
    }
    Olepe[(((b * 56) + y) * 56 + x) * 256 + c] = __float2bfloat16(a);
}

// ---------------------------------------------------------------------------
// K6: gathered window attention, one block per (window, head, batch)
//     Q 64x32 (regs, pre-scaled), K/V 256x32 in LDS (stride 33)
// ---------------------------------------------------------------------------
__global__ __launch_bounds__(256) void k_attn(
    const __hip_bfloat16* __restrict__ QKV,
    const int* __restrict__ ridx,
    __hip_bfloat16* __restrict__ Oattn)
{
    __shared__ float Ks[256][33];   // later reused as Opart[seg][q][d]
    __shared__ float Vs[256][33];
    __shared__ float mred[4][64];
    __shared__ float lred[4][64];
    const int p = blockIdx.x, head = blockIdx.y, b = blockIdx.z;
    const int t = threadIdx.x;
    const int wi = p / 7, wj = p % 7;
    const int q = t & 63, seg = t >> 6, k0 = seg << 6;

    // load K/V: thread t owns key t (window ridx[t>>6], pixel t&63)
    {
        int sel = ridx[(b * 49 + p) * 4 + (t >> 6)];
        int si = sel / 7, sj = sel % 7;
        int pp = t & 63;
        int y = si * 8 + (pp >> 3), x = sj * 8 + (pp & 7);
        const __hip_bfloat16* base = &QKV[(((b * 56) + y) * 56 + x) * 768 + 256 + head * 32];
        #pragma unroll
        for (int c = 0; c < 4; c++) {
            float4 k4 = *reinterpret_cast<const float4*>(base + c * 8);
            float4 v4 = *reinterpret_cast<const float4*>(base + 256 + c * 8);
            const unsigned short* ku = reinterpret_cast<const unsigned short*>(&k4);
            const unsigned short* vu = reinterpret_cast<const unsigned short*>(&v4);
            #pragma unroll
            for (int i = 0; i < 8; i++) {
                Ks[t][c * 8 + i] = bf2f(ku[i]);
                Vs[t][c * 8 + i] = bf2f(vu[i]);
            }
        }
    }
    // Q row into registers, pre-scaled by 1/16
    float qreg[32];
    {
        int y = wi * 8 + (q >> 3), x = wj * 8 + (q & 7);
        const __hip_bfloat16* qp = &QKV[(((b * 56) + y) * 56 + x) * 768 + head * 32];
        #pragma unroll
        for (int c = 0; c < 4; c++) {
            float4 q4 = *reinterpret_cast<const float4*>(qp + c * 8);
            const unsigned short* qu = reinterpret_cast<const unsigned short*>(&q4);
            #pragma unroll
            for (int i = 0; i < 8; i++) qreg[c * 8 + i] = bf2f(qu[i]) * 0.0625f;
        }
    }
    __syncthreads();

    // scores for this thread's 64-key segment
    float s[64];
    float mloc = -1e30f;
    #pragma unroll
    for (int k = 0; k < 64; k++) {
        float a = 0.f;
        #pragma unroll
        for (int d = 0; d < 32; d++) a += qreg[d] * Ks[k0 + k][d];
        s[k] = a;
        mloc = fmaxf(mloc, a);
    }
    mred[seg][q] = mloc;
    __syncthreads();   // also: everyone done reading Ks
    const float M = fmaxf(fmaxf(mred[0][q], mred[1][q]), fmaxf(mred[2][q], mred[3][q]));

    float accv[32];
    #pragma unroll
    for (int d = 0; d < 32; d++) accv[d] = 0.f;
    float l = 0.f;
    #pragma unroll
    for (int k = 0; k < 64; k++) {
        float pe = __expf(s[k] - M);
        l += pe;
        #pragma unroll
        for (int d = 0; d < 32; d++) accv[d] += pe * Vs[k0 + k][d];
    }
    lred[seg][q] = l;
    #pragma unroll
    for (int d = 0; d < 32; d++) Ks[k0 + q][d] = accv[d];   // Opart alias (Ks dead)
    __syncthreads();

    const float L = lred[0][q] + lred[1][q] + lred[2][q] + lred[3][q];
    const float inv = 1.0f / L;
    int y = wi * 8 + (q >> 3), x = wj * 8 + (q & 7);
    __hip_bfloat16* op = &Oattn[(((b * 56) + y) * 56 + x) * 256 + head * 32];
    #pragma unroll
    for (int dd = 0; dd < 8; dd++) {
        int d = (seg << 3) + dd;
        op[d] = __float2bfloat16(
            (Ks[0 * 64 + q][d] + Ks[1 * 64 + q][d] + Ks[2 * 64 + q][d] + Ks[3 * 64 + q][d]) * inv);
    }
}

// ---------------------------------------------------------------------------
// K7: output proj  (Oattn + Olepe)[12544,256](bf16) x Wo[256,256](f32) + bo
//     -> fp32 out (reference output dtype)
// ---------------------------------------------------------------------------
__global__ __launch_bounds__(256) void k_proj(
    const __hip_bfloat16* __restrict__ A1, const __hip_bfloat16* __restrict__ A2,
    const float* __restrict__ W,
    const float* __restrict__ bias,
    float* __restrict__ O)
{
    __shared__ float As[16][65];
    __shared__ float Bs[16][65];
    const int m0 = blockIdx.x * 64;
    const int n0 = blockIdx.y * 64;
    const int t  = threadIdx.x;
    const int tx = t & 15, ty = t >> 4;
    const int arow = t >> 2, akq = (t & 3) << 2;
    const int brow = t >> 4, bnq = (t & 15) << 2;
    float acc[4][4] = {};
    for (int kt = 0; kt < 256; kt += 16) {
        ushort4 a1 = *reinterpret_cast<const ushort4*>(
            reinterpret_cast<const unsigned short*>(A1) + (m0 + arow) * 256 + kt + akq);
        ushort4 a2 = *reinterpret_cast<const ushort4*>(
            reinterpret_cast<const unsigned short*>(A2) + (m0 + arow) * 256 + kt + akq);
        float4 bv = *reinterpret_cast<const float4*>(&W[(kt + brow) * 256 + n0 + bnq]);
        As[akq + 0][arow] = bf2f(a1.x) + bf2f(a2.x);
        As[akq + 1][arow] = bf2f(a1.y) + bf2f(a2.y);
        As[akq + 2][arow] = bf2f(a1.z) + bf2f(a2.z);
        As[akq + 3][arow] = bf2f(a1.w) + bf2f(a2.w);
        Bs[brow][bnq + 0] = bv.x;
        Bs[brow][bnq + 1] = bv.y;
        Bs[brow][bnq + 2] = bv.z;
        Bs[brow][bnq + 3] = bv.w;
        __syncthreads();
        #pragma unroll
        for (int kk = 0; kk < 16; kk++) {
            float a[4], b[4];
            #pragma unroll
            for (int i = 0; i < 4; i++) a[i] = As[kk][ty + 16 * i];
            #pragma unroll
            for (int j = 0; j < 4; j++) b[j] = Bs[kk][tx + 16 * j];
            #pragma unroll
            for (int i = 0; i < 4; i++)
                #pragma unroll
                for (int j = 0; j < 4; j++)
                    acc[i][j] += a[i] * b[j];
        }
        __syncthreads();
    }
    #pragma unroll
    for (int j = 0; j < 4; j++) {
        int n = n0 + tx + 16 * j;
        float bb = bias[n];
        #pragma unroll
        for (int i = 0; i < 4; i++) {
            int m = m0 + ty + 16 * i;
            O[m * 256 + n] = acc[i][j] + bb;
        }
    }
}

// ---------------------------------------------------------------------------
extern "C" void kernel_launch(void* const* d_in, const int* in_sizes, int n_in,
                              void* d_out, int out_size, void* d_ws, size_t ws_size,
                              hipStream_t stream)
{
    const float* x    = (const float*)d_in[0];
    const float* Wqkv = (const float*)d_in[1];
    const float* bqkv = (const float*)d_in[2];
    const float* Wo   = (const float*)d_in[3];
    const float* bo   = (const float*)d_in[4];
    const float* lw   = (const float*)d_in[5];
    const float* lb   = (const float*)d_in[6];
    float* out = (float*)d_out;

    char* ws = (char*)d_ws;
    size_t off = 0;
    __hip_bfloat16* qkv   = (__hip_bfloat16*)(ws + off); off += (size_t)NPIX * 768 * 2;  // 19,267,584
    __hip_bfloat16* Oattn = (__hip_bfloat16*)(ws + off); off += (size_t)NPIX * 256 * 2;  //  6,422,528
    __hip_bfloat16* Olepe = (__hip_bfloat16*)(ws + off); off += (size_t)NPIX * 256 * 2;  //  6,422,528
    float* xmean = (float*)(ws + off); off += 196 * 256 * 4;
    float* qwin  = (float*)(ws + off); off += 196 * 256 * 4;
    float* kwin  = (float*)(ws + off); off += 196 * 256 * 4;
    int*   ridx  = (int*)(ws + off);   off += 196 * 4 * 4;

    k_qkv_gemm<<<dim3(196, 12), 256, 0, stream>>>(x, Wqkv, bqkv, qkv);
    k_xmean  <<<dim3(196),      256, 0, stream>>>(x, xmean);
    k_winproj<<<dim3(196),      256, 0, stream>>>(xmean, Wqkv, bqkv, qwin, kwin);
    k_route  <<<dim3(4),        256, 0, stream>>>(qwin, kwin, ridx);
    k_lepe   <<<dim3(12544),    256, 0, stream>>>(qkv, lw, lb, Olepe);
    k_attn   <<<dim3(49, 8, 4), 256, 0, stream>>>(qkv, ridx, Oattn);
    k_proj   <<<dim3(196, 4),   256, 0, stream>>>(Oattn, Olepe, Wo, bo, out);
}

// Round 4
// 212.764 us; speedup vs baseline: 2.7426x; 2.7426x over previous
//
#include <hip/hip_runtime.h>
#include <hip/hip_bf16.h>

// B=4, H=W=56, C=256, 7x7 windows of 8x8, 8 heads x 32, top-4.
// Inputs fp32; d_out fp32. Intermediates bf16; MFMA bf16 w/ fp32 accum.
#define NPIX 12544   // B*56*56

typedef short bf16x8 __attribute__((ext_vector_type(8)));
typedef float f32x4  __attribute__((ext_vector_type(4)));

__device__ __forceinline__ float bf2f(unsigned short u) {
    unsigned int x = ((unsigned int)u) << 16;
    float f; __builtin_memcpy(&f, &x, sizeof(f)); return f;
}
__device__ __forceinline__ unsigned short f2bf(float f) {
    __hip_bfloat16 h = __float2bfloat16(f);
    unsigned short u; __builtin_memcpy(&u, &h, 2); return u;
}

// ---------------------------------------------------------------------------
// Prep: x -> bf16 (vectorized)
// ---------------------------------------------------------------------------
__global__ __launch_bounds__(256) void k_cvt_x(
    const float* __restrict__ X, unsigned short* __restrict__ Xb)
{
    int idx = blockIdx.x * 256 + threadIdx.x;           // 802816 = NPIX*256/4
    float4 v = reinterpret_cast<const float4*>(X)[idx];
    ushort4 o = { f2bf(v.x), f2bf(v.y), f2bf(v.z), f2bf(v.w) };
    reinterpret_cast<ushort4*>(Xb)[idx] = o;
}

// Prep: Wqkv^T and Wo^T -> bf16 [n][k]
__global__ __launch_bounds__(256) void k_cvt_w(
    const float* __restrict__ Wqkv, const float* __restrict__ Wo,
    unsigned short* __restrict__ Wtq, unsigned short* __restrict__ Wto)
{
    int tg = blockIdx.x * 256 + threadIdx.x;            // 262144 total
    if (tg < 196608) {
        int n = tg >> 8, k = tg & 255;
        Wtq[tg] = f2bf(Wqkv[k * 768 + n]);
    } else {
        int u = tg - 196608;
        int n = u >> 8, k = u & 255;
        Wto[u] = f2bf(Wo[k * 256 + n]);
    }
}

// ---------------------------------------------------------------------------
// K1: qkv GEMM (MFMA)  xb[12544,256] @ Wqkv[256,768] + bqkv -> qkv bf16
//     128x128 tile, BK=32, 4 waves (2x2), wave tile 64x64 (4x4 mfma tiles)
// ---------------------------------------------------------------------------
__global__ __launch_bounds__(256) void k_qkv_gemm(
    const unsigned short* __restrict__ A,   // xb [12544][256]
    const unsigned short* __restrict__ Bt,  // Wtq [768][256] (= Wqkv^T)
    const float* __restrict__ bias,         // [768]
    unsigned short* __restrict__ O)         // qkv bf16 [12544][768]
{
    __shared__ unsigned short As[128 * 40];
    __shared__ unsigned short Bs[128 * 40];
    const int t = threadIdx.x;
    const int m0 = blockIdx.x * 128, n0 = blockIdx.y * 128;
    const int wave = t >> 6, lane = t & 63, quad = lane >> 4, lo = lane & 15;
    const int wm = wave & 1, wn = wave >> 1;
    const int srow = t >> 1, sh = t & 1;
    f32x4 acc[4][4];
    #pragma unroll
    for (int i = 0; i < 4; i++)
        #pragma unroll
        for (int j = 0; j < 4; j++) acc[i][j] = (f32x4){0.f, 0.f, 0.f, 0.f};

    for (int kt = 0; kt < 256; kt += 32) {
        const unsigned short* ag = A  + (m0 + srow) * 256 + kt + sh * 16;
        const unsigned short* bg = Bt + (n0 + srow) * 256 + kt + sh * 16;
        bf16x8 a0 = *reinterpret_cast<const bf16x8*>(ag);
        bf16x8 a1 = *reinterpret_cast<const bf16x8*>(ag + 8);
        bf16x8 b0 = *reinterpret_cast<const bf16x8*>(bg);
        bf16x8 b1 = *reinterpret_cast<const bf16x8*>(bg + 8);
        int g  = (srow >> 3) & 3;
        int c0 = (sh * 2) ^ g, c1 = (sh * 2 + 1) ^ g;
        __syncthreads();   // previous-iter readers done
        *reinterpret_cast<bf16x8*>(&As[srow * 40 + c0 * 8]) = a0;
        *reinterpret_cast<bf16x8*>(&As[srow * 40 + c1 * 8]) = a1;
        *reinterpret_cast<bf16x8*>(&Bs[srow * 40 + c0 * 8]) = b0;
        *reinterpret_cast<bf16x8*>(&Bs[srow * 40 + c1 * 8]) = b1;
        __syncthreads();
        bf16x8 af[4], bfr[4];
        #pragma unroll
        for (int mt = 0; mt < 4; mt++) {
            int row = wm * 64 + mt * 16 + lo;
            af[mt] = *reinterpret_cast<const bf16x8*>(
                &As[row * 40 + ((quad ^ ((row >> 3) & 3)) * 8)]);
        }
        #pragma unroll
        for (int nt = 0; nt < 4; nt++) {
            int col = wn * 64 + nt * 16 + lo;
            bfr[nt] = *reinterpret_cast<const bf16x8*>(
                &Bs[col * 40 + ((quad ^ ((col >> 3) & 3)) * 8)]);
        }
        #pragma unroll
        for (int mt = 0; mt < 4; mt++)
            #pragma unroll
            for (int nt = 0; nt < 4; nt++)
                acc[mt][nt] = __builtin_amdgcn_mfma_f32_16x16x32_bf16(
                    af[mt], bfr[nt], acc[mt][nt], 0, 0, 0);
    }
    float bv[4];
    #pragma unroll
    for (int nt = 0; nt < 4; nt++) bv[nt] = bias[n0 + wn * 64 + nt * 16 + lo];
    #pragma unroll
    for (int mt = 0; mt < 4; mt++)
        #pragma unroll
        for (int nt = 0; nt < 4; nt++) {
            int n = n0 + wn * 64 + nt * 16 + lo;
            #pragma unroll
            for (int r = 0; r < 4; r++) {
                int m = m0 + wm * 64 + mt * 16 + quad * 4 + r;
                O[m * 768 + n] = f2bf(acc[mt][nt][r] + bv[nt]);
            }
        }
}

// ---------------------------------------------------------------------------
// K2: per-window mean of x (fp32 exact routing path)
// ---------------------------------------------------------------------------
__global__ __launch_bounds__(256) void k_xmean(
    const float* __restrict__ X, float* __restrict__ xmean)
{
    const int bp = blockIdx.x;
    const int b = bp / 49, p = bp % 49;
    const int wi = p / 7, wj = p % 7;
    const int c = threadIdx.x;
    float s = 0.f;
    for (int pp = 0; pp < 64; pp++) {
        int y = wi * 8 + (pp >> 3), x = wj * 8 + (pp & 7);
        s += X[(((b * 56) + y) * 56 + x) * 256 + c];
    }
    xmean[bp * 256 + c] = s * (1.0f / 64.0f);
}

// ---------------------------------------------------------------------------
// K3: q_win / k_win = xmean @ Wqkv[:, 0:512] + bqkv (fp32 exact)
// ---------------------------------------------------------------------------
__global__ __launch_bounds__(256) void k_winproj(
    const float* __restrict__ xmean,
    const float* __restrict__ W,
    const float* __restrict__ bias,
    float* __restrict__ qwin, float* __restrict__ kwin)
{
    __shared__ float xs[256];
    const int bp = blockIdx.x;
    const int c = threadIdx.x;
    xs[c] = xmean[bp * 256 + c];
    __syncthreads();
    float aq = 0.f, ak = 0.f;
    for (int k = 0; k < 256; k++) {
        float xv = xs[k];
        aq += xv * W[k * 768 + c];
        ak += xv * W[k * 768 + 256 + c];
    }
    qwin[bp * 256 + c] = aq + bias[c];
    kwin[bp * 256 + c] = ak + bias[256 + c];
}

// ---------------------------------------------------------------------------
// K4: routing logits + top-4, one block per (b, p)
// ---------------------------------------------------------------------------
__global__ __launch_bounds__(256) void k_route(
    const float* __restrict__ qwin, const float* __restrict__ kwin,
    int* __restrict__ ridx)
{
    __shared__ float part[49][4];
    __shared__ float lg[49];
    const int bp = blockIdx.x;
    const int b = bp / 49, p = bp % 49;
    const int t = threadIdx.x;
    if (t < 196) {
        int d = t >> 2, pr = t & 3;
        const float* qp = &qwin[(b * 49 + p) * 256];
        const float* kp = &kwin[(b * 49 + d) * 256];
        float a = 0.f;
        for (int ch = pr * 64; ch < pr * 64 + 64; ch++) a += qp[ch] * kp[ch];
        part[d][pr] = a;
    }
    __syncthreads();
    if (t < 49) lg[t] = (part[t][0] + part[t][1] + part[t][2] + part[t][3]);
    __syncthreads();
    if (t == 0) {
        unsigned long long used = 0ull;
        for (int sel = 0; sel < 4; sel++) {
            float best = -1e30f; int bi = 0;
            for (int qq = 0; qq < 49; qq++)
                if (!((used >> qq) & 1ull) && lg[qq] > best) { best = lg[qq]; bi = qq; }
            used |= (1ull << bi);
            ridx[bp * 4 + sel] = bi;
        }
    }
}

// ---------------------------------------------------------------------------
// K5: depthwise 5x5 LEPE conv on v channels -> bf16
// ---------------------------------------------------------------------------
__global__ __launch_bounds__(256) void k_lepe(
    const unsigned short* __restrict__ QKV,
    const float* __restrict__ lw, const float* __restrict__ lb,
    unsigned short* __restrict__ Olepe)
{
    const int blk = blockIdx.x;
    const int b = blk / 3136, rem = blk % 3136;
    const int y = rem / 56, x = rem % 56;
    const int c = threadIdx.x;
    float a = lb[c];
    #pragma unroll
    for (int ky = 0; ky < 5; ky++) {
        int yy = y + ky - 2;
        if (yy < 0 || yy >= 56) continue;
        #pragma unroll
        for (int kx = 0; kx < 5; kx++) {
            int xx = x + kx - 2;
            if (xx < 0 || xx >= 56) continue;
            a += bf2f(QKV[(((b * 56) + yy) * 56 + xx) * 768 + 512 + c]) *
                 lw[(ky * 5 + kx) * 256 + c];
        }
    }
    Olepe[(((b * 56) + y) * 56 + x) * 256 + c] = f2bf(a);
}

// ---------------------------------------------------------------------------
// K6: MFMA gathered window attention; block = (p, head, b), 4 waves.
//     QK^T: 16x16x32 mfma (K=d=32), softmax in regs (shfl over 16-lane groups),
//     P -> per-wave LDS (bf16), PV: mfma with V^T staged [d][key].
// ---------------------------------------------------------------------------
__global__ __launch_bounds__(256) void k_attn(
    const unsigned short* __restrict__ QKV,
    const int* __restrict__ ridx,
    unsigned short* __restrict__ Oattn)
{
    __shared__ __align__(16) unsigned char smem[50688];
    unsigned short* Vt = (unsigned short*)smem;                  // [32][264]
    unsigned short* Qs = (unsigned short*)(smem + 16896);        // [64][40]
    unsigned short* Ks = (unsigned short*)(smem + 22016);        // [256][40]
    unsigned short* Ps = (unsigned short*)(smem + 16896);        // 4 x [16][264] (over Qs/Ks)

    const int p = blockIdx.x, head = blockIdx.y, b = blockIdx.z;
    const int t = threadIdx.x;
    const int wi = p / 7, wj = p % 7;
    const int wave = t >> 6, lane = t & 63, quad = lane >> 4, lo = lane & 15;
    const int pix4 = t >> 2, c4 = t & 3;          // 4 lanes per pixel, 64 pixels/pass

    // ---- load Q (64 pix x 32 ch) ----
    {
        int y = wi * 8 + (pix4 >> 3), x = wj * 8 + (pix4 & 7);
        const unsigned short* qp = QKV + (((b * 56) + y) * 56 + x) * 768 + head * 32 + c4 * 8;
        bf16x8 v = *reinterpret_cast<const bf16x8*>(qp);
        int sw = c4 ^ ((pix4 >> 3) & 3);
        *reinterpret_cast<bf16x8*>(&Qs[pix4 * 40 + sw * 8]) = v;
    }
    // ---- load gathered K (row-major) and V (transposed) ----
    #pragma unroll
    for (int pass = 0; pass < 4; pass++) {
        int sel = ridx[(b * 49 + p) * 4 + pass];
        int si = sel / 7, sj = sel % 7;
        int y = si * 8 + (pix4 >> 3), x = sj * 8 + (pix4 & 7);
        const unsigned short* base = QKV + (((b * 56) + y) * 56 + x) * 768 + 256 + head * 32;
        bf16x8 kv = *reinterpret_cast<const bf16x8*>(base + c4 * 8);
        bf16x8 vv = *reinterpret_cast<const bf16x8*>(base + 256 + c4 * 8);
        int krow = pass * 64 + pix4;
        int sw = c4 ^ ((krow >> 3) & 3);
        *reinterpret_cast<bf16x8*>(&Ks[krow * 40 + sw * 8]) = kv;
        #pragma unroll
        for (int j = 0; j < 8; j++)
            Vt[(c4 * 8 + j) * 264 + krow] = (unsigned short)vv[j];
    }
    __syncthreads();

    // ---- QK^T: wave handles q rows wave*16..+15 vs all 256 keys ----
    f32x4 sc[16];
    {
        int row = wave * 16 + lo;
        bf16x8 af = *reinterpret_cast<const bf16x8*>(
            &Qs[row * 40 + ((quad ^ ((row >> 3) & 3)) * 8)]);
        f32x4 z = (f32x4){0.f, 0.f, 0.f, 0.f};
        #pragma unroll
        for (int nt = 0; nt < 16; nt++) {
            int key = nt * 16 + lo;
            bf16x8 bfr = *reinterpret_cast<const bf16x8*>(
                &Ks[key * 40 + ((quad ^ ((key >> 3) & 3)) * 8)]);
            sc[nt] = __builtin_amdgcn_mfma_f32_16x16x32_bf16(af, bfr, z, 0, 0, 0);
        }
    }
    // ---- softmax over 256 keys per q-row (rows quad*4+r, spread over 16 lanes) ----
    float M[4] = {-1e30f, -1e30f, -1e30f, -1e30f};
    #pragma unroll
    for (int nt = 0; nt < 16; nt++)
        #pragma unroll
        for (int r = 0; r < 4; r++) M[r] = fmaxf(M[r], sc[nt][r] * 0.0625f);
    #pragma unroll
    for (int d = 1; d < 16; d <<= 1)
        #pragma unroll
        for (int r = 0; r < 4; r++) M[r] = fmaxf(M[r], __shfl_xor(M[r], d));
    float l[4] = {0.f, 0.f, 0.f, 0.f};
    #pragma unroll
    for (int nt = 0; nt < 16; nt++)
        #pragma unroll
        for (int r = 0; r < 4; r++) {
            float e = __expf(sc[nt][r] * 0.0625f - M[r]);
            sc[nt][r] = e;
            l[r] += e;
        }
    #pragma unroll
    for (int d = 1; d < 16; d <<= 1)
        #pragma unroll
        for (int r = 0; r < 4; r++) l[r] += __shfl_xor(l[r], d);

    __syncthreads();   // all waves done reading Qs/Ks -> Ps may overwrite

    // ---- write P (bf16) to this wave's LDS tile [16][264] ----
    unsigned short* myPs = Ps + wave * 16 * 264;
    #pragma unroll
    for (int nt = 0; nt < 16; nt++)
        #pragma unroll
        for (int r = 0; r < 4; r++)
            myPs[(quad * 4 + r) * 264 + nt * 16 + lo] = f2bf(sc[nt][r]);
    __syncthreads();   // conservative: ensure P visible before frag reads

    // ---- PV: O[16 q x 32 d] = P[16x256] @ V[256x32], via Vt[d][key] ----
    f32x4 o0 = (f32x4){0.f, 0.f, 0.f, 0.f}, o1 = o0;
    #pragma unroll
    for (int kt = 0; kt < 8; kt++) {
        bf16x8 pa = *reinterpret_cast<const bf16x8*>(
            &myPs[lo * 264 + kt * 32 + quad * 8]);
        bf16x8 vb0 = *reinterpret_cast<const bf16x8*>(
            &Vt[lo * 264 + kt * 32 + quad * 8]);
        bf16x8 vb1 = *reinterpret_cast<const bf16x8*>(
            &Vt[(16 + lo) * 264 + kt * 32 + quad * 8]);
        o0 = __builtin_amdgcn_mfma_f32_16x16x32_bf16(pa, vb0, o0, 0, 0, 0);
        o1 = __builtin_amdgcn_mfma_f32_16x16x32_bf16(pa, vb1, o1, 0, 0, 0);
    }
    // ---- epilogue: divide by L, store bf16 to image layout ----
    #pragma unroll
    for (int r = 0; r < 4; r++) {
        int q = wave * 16 + quad * 4 + r;
        int y = wi * 8 + (q >> 3), x = wj * 8 + (q & 7);
        unsigned short* op = Oattn + (((b * 56) + y) * 56 + x) * 256 + head * 32;
        float inv = 1.0f / l[r];
        op[lo]      = f2bf(o0[r] * inv);
        op[16 + lo] = f2bf(o1[r] * inv);
    }
}

// ---------------------------------------------------------------------------
// K7: out proj (MFMA): (Oattn+Olepe)[12544,256] @ Wo[256,256] + bo -> fp32 out
//     128x64 tile, 4 waves stacked on M, wave tile 32x64 (2x4 mfma tiles)
// ---------------------------------------------------------------------------
__global__ __launch_bounds__(256) void k_proj(
    const unsigned short* __restrict__ A1, const unsigned short* __restrict__ A2,
    const unsigned short* __restrict__ Bt,   // Wto [256][256] (= Wo^T)
    const float* __restrict__ bias,
    float* __restrict__ O)
{
    __shared__ unsigned short As[128 * 40];
    __shared__ unsigned short Bs[64 * 40];
    const int t = threadIdx.x;
    const int m0 = blockIdx.x * 128, n0 = blockIdx.y * 64;
    const int wave = t >> 6, lane = t & 63, quad = lane >> 4, lo = lane & 15;
    const int srow = t >> 1, sh = t & 1;     // A staging
    const int brow = t >> 2, bc = t & 3;     // B staging
    f32x4 acc[2][4];
    #pragma unroll
    for (int i = 0; i < 2; i++)
        #pragma unroll
        for (int j = 0; j < 4; j++) acc[i][j] = (f32x4){0.f, 0.f, 0.f, 0.f};

    for (int kt = 0; kt < 256; kt += 32) {
        const unsigned short* a1g = A1 + (m0 + srow) * 256 + kt + sh * 16;
        const unsigned short* a2g = A2 + (m0 + srow) * 256 + kt + sh * 16;
        bf16x8 x0 = *reinterpret_cast<const bf16x8*>(a1g);
        bf16x8 x1 = *reinterpret_cast<const bf16x8*>(a1g + 8);
        bf16x8 y0 = *reinterpret_cast<const bf16x8*>(a2g);
        bf16x8 y1 = *reinterpret_cast<const bf16x8*>(a2g + 8);
        bf16x8 bgv = *reinterpret_cast<const bf16x8*>(
            Bt + (n0 + brow) * 256 + kt + bc * 8);
        bf16x8 s0, s1;
        #pragma unroll
        for (int j = 0; j < 8; j++) {
            s0[j] = (short)f2bf(bf2f((unsigned short)x0[j]) + bf2f((unsigned short)y0[j]));
            s1[j] = (short)f2bf(bf2f((unsigned short)x1[j]) + bf2f((unsigned short)y1[j]));
        }
        int g  = (srow >> 3) & 3;
        int c0 = (sh * 2) ^ g, c1 = (sh * 2 + 1) ^ g;
        int gb = (brow >> 3) & 3;
        __syncthreads();
        *reinterpret_cast<bf16x8*>(&As[srow * 40 + c0 * 8]) = s0;
        *reinterpret_cast<bf16x8*>(&As[srow * 40 + c1 * 8]) = s1;
        *reinterpret_cast<bf16x8*>(&Bs[brow * 40 + ((bc ^ gb) * 8)]) = bgv;
        __syncthreads();
        bf16x8 af[2], bfr[4];
        #pragma unroll
        for (int mt = 0; mt < 2; mt++) {
            int row = wave * 32 + mt * 16 + lo;
            af[mt] = *reinterpret_cast<const bf16x8*>(
                &As[row * 40 + ((quad ^ ((row >> 3) & 3)) * 8)]);
        }
        #pragma unroll
        for (int nt = 0; nt < 4; nt++) {
            int col = nt * 16 + lo;
            bfr[nt] = *reinterpret_cast<const bf16x8*>(
                &Bs[col * 40 + ((quad ^ ((col >> 3) & 3)) * 8)]);
        }
        #pragma unroll
        for (int mt = 0; mt < 2; mt++)
            #pragma unroll
            for (int nt = 0; nt < 4; nt++)
                acc[mt][nt] = __builtin_amdgcn_mfma_f32_16x16x32_bf16(
                    af[mt], bfr[nt], acc[mt][nt], 0, 0, 0);
    }
    float bv[4];
    #pragma unroll
    for (int nt = 0; nt < 4; nt++) bv[nt] = bias[n0 + nt * 16 + lo];
    #pragma unroll
    for (int mt = 0; mt < 2; mt++)
        #pragma unroll
        for (int nt = 0; nt < 4; nt++) {
            int n = n0 + nt * 16 + lo;
            #pragma unroll
            for (int r = 0; r < 4; r++) {
                int m = m0 + wave * 32 + mt * 16 + quad * 4 + r;
                O[m * 256 + n] = acc[mt][nt][r] + bv[nt];
            }
        }
}

// ---------------------------------------------------------------------------
extern "C" void kernel_launch(void* const* d_in, const int* in_sizes, int n_in,
                              void* d_out, int out_size, void* d_ws, size_t ws_size,
                              hipStream_t stream)
{
    const float* x    = (const float*)d_in[0];
    const float* Wqkv = (const float*)d_in[1];
    const float* bqkv = (const float*)d_in[2];
    const float* Wo   = (const float*)d_in[3];
    const float* bo   = (const float*)d_in[4];
    const float* lw   = (const float*)d_in[5];
    const float* lb   = (const float*)d_in[6];
    float* out = (float*)d_out;

    char* ws = (char*)d_ws;
    size_t off = 0;
    unsigned short* qkv   = (unsigned short*)(ws + off); off += (size_t)NPIX * 768 * 2;
    unsigned short* xb    = (unsigned short*)(ws + off); off += (size_t)NPIX * 256 * 2;
    unsigned short* Wtq   = (unsigned short*)(ws + off); off += 768 * 256 * 2;
    unsigned short* Wto   = (unsigned short*)(ws + off); off += 256 * 256 * 2;
    unsigned short* Oattn = (unsigned short*)(ws + off); off += (size_t)NPIX * 256 * 2;
    unsigned short* Olepe = (unsigned short*)(ws + off); off += (size_t)NPIX * 256 * 2;
    float* xmean = (float*)(ws + off); off += 196 * 256 * 4;
    float* qwin  = (float*)(ws + off); off += 196 * 256 * 4;
    float* kwin  = (float*)(ws + off); off += 196 * 256 * 4;
    int*   ridx  = (int*)(ws + off);   off += 196 * 4 * 4;

    k_cvt_x   <<<dim3(3136),     256, 0, stream>>>(x, xb);
    k_cvt_w   <<<dim3(1024),     256, 0, stream>>>(Wqkv, Wo, Wtq, Wto);
    k_qkv_gemm<<<dim3(98, 6),    256, 0, stream>>>(xb, Wtq, bqkv, qkv);
    k_xmean   <<<dim3(196),      256, 0, stream>>>(x, xmean);
    k_winproj <<<dim3(196),      256, 0, stream>>>(xmean, Wqkv, bqkv, qwin, kwin);
    k_route   <<<dim3(196),      256, 0, stream>>>(qwin, kwin, ridx);
    k_lepe    <<<dim3(12544),    256, 0, stream>>>(qkv, lw, lb, Olepe);
    k_attn    <<<dim3(49, 8, 4), 256, 0, stream>>>(qkv, ridx, Oattn);
    k_proj    <<<dim3(98, 4),    256, 0, stream>>>(Oattn, Olepe, Wto, bo, out);
}

// Round 5
// 180.901 us; speedup vs baseline: 3.2256x; 1.1761x over previous
//
#include <hip/hip_runtime.h>
#include <hip/hip_bf16.h>

// B=4, H=W=56, C=256, 7x7 windows of 8x8, 8 heads x 32, top-4.
// Inputs fp32; d_out fp32. Intermediates bf16; MFMA bf16 w/ fp32 accum.
#define NPIX 12544   // B*56*56

typedef short bf16x8 __attribute__((ext_vector_type(8)));
typedef float f32x4  __attribute__((ext_vector_type(4)));

__device__ __forceinline__ float bf2f(unsigned short u) {
    unsigned int x = ((unsigned int)u) << 16;
    float f; __builtin_memcpy(&f, &x, sizeof(f)); return f;
}
__device__ __forceinline__ unsigned short f2bf(float f) {
    __hip_bfloat16 h = __float2bfloat16(f);
    unsigned short u; __builtin_memcpy(&u, &h, 2); return u;
}

// ---------------------------------------------------------------------------
// Prep A: fused x->bf16 conversion + per-window mean (reads x once)
//   block = (b, window); threads = 256 channels
// ---------------------------------------------------------------------------
__global__ __launch_bounds__(256) void k_prep_x(
    const float* __restrict__ X, unsigned short* __restrict__ Xb,
    float* __restrict__ xmean)
{
    const int bp = blockIdx.x;            // 0..195
    const int b = bp / 49, p = bp % 49;
    const int wi = p / 7, wj = p % 7;
    const int c = threadIdx.x;
    float s = 0.f;
    #pragma unroll 4
    for (int pp = 0; pp < 64; pp++) {
        int y = wi * 8 + (pp >> 3), x = wj * 8 + (pp & 7);
        int idx = (((b * 56) + y) * 56 + x) * 256 + c;
        float v = X[idx];
        s += v;
        Xb[idx] = f2bf(v);
    }
    xmean[bp * 256 + c] = s * (1.0f / 64.0f);
}

// Prep B: Wqkv^T and Wo^T -> bf16 [n][k]
__global__ __launch_bounds__(256) void k_cvt_w(
    const float* __restrict__ Wqkv, const float* __restrict__ Wo,
    unsigned short* __restrict__ Wtq, unsigned short* __restrict__ Wto)
{
    int tg = blockIdx.x * 256 + threadIdx.x;            // 262144 total
    if (tg < 196608) {
        int n = tg >> 8, k = tg & 255;
        Wtq[tg] = f2bf(Wqkv[k * 768 + n]);
    } else {
        int u = tg - 196608;
        int n = u >> 8, k = u & 255;
        Wto[u] = f2bf(Wo[k * 256 + n]);
    }
}

// ---------------------------------------------------------------------------
// K1: qkv GEMM (MFMA)  xb[12544,256] @ Wqkv[256,768] + bqkv -> qkv bf16
//     128x128 tile, BK=32, 4 waves (2x2), wave tile 64x64 (4x4 mfma tiles)
// ---------------------------------------------------------------------------
__global__ __launch_bounds__(256) void k_qkv_gemm(
    const unsigned short* __restrict__ A,   // xb [12544][256]
    const unsigned short* __restrict__ Bt,  // Wtq [768][256] (= Wqkv^T)
    const float* __restrict__ bias,         // [768]
    unsigned short* __restrict__ O)         // qkv bf16 [12544][768]
{
    __shared__ unsigned short As[128 * 40];
    __shared__ unsigned short Bs[128 * 40];
    const int t = threadIdx.x;
    const int m0 = blockIdx.x * 128, n0 = blockIdx.y * 128;
    const int wave = t >> 6, lane = t & 63, quad = lane >> 4, lo = lane & 15;
    const int wm = wave & 1, wn = wave >> 1;
    const int srow = t >> 1, sh = t & 1;
    f32x4 acc[4][4];
    #pragma unroll
    for (int i = 0; i < 4; i++)
        #pragma unroll
        for (int j = 0; j < 4; j++) acc[i][j] = (f32x4){0.f, 0.f, 0.f, 0.f};

    for (int kt = 0; kt < 256; kt += 32) {
        const unsigned short* ag = A  + (m0 + srow) * 256 + kt + sh * 16;
        const unsigned short* bg = Bt + (n0 + srow) * 256 + kt + sh * 16;
        bf16x8 a0 = *reinterpret_cast<const bf16x8*>(ag);
        bf16x8 a1 = *reinterpret_cast<const bf16x8*>(ag + 8);
        bf16x8 b0 = *reinterpret_cast<const bf16x8*>(bg);
        bf16x8 b1 = *reinterpret_cast<const bf16x8*>(bg + 8);
        int g  = (srow >> 3) & 3;
        int c0 = (sh * 2) ^ g, c1 = (sh * 2 + 1) ^ g;
        __syncthreads();   // previous-iter readers done
        *reinterpret_cast<bf16x8*>(&As[srow * 40 + c0 * 8]) = a0;
        *reinterpret_cast<bf16x8*>(&As[srow * 40 + c1 * 8]) = a1;
        *reinterpret_cast<bf16x8*>(&Bs[srow * 40 + c0 * 8]) = b0;
        *reinterpret_cast<bf16x8*>(&Bs[srow * 40 + c1 * 8]) = b1;
        __syncthreads();
        bf16x8 af[4], bfr[4];
        #pragma unroll
        for (int mt = 0; mt < 4; mt++) {
            int row = wm * 64 + mt * 16 + lo;
            af[mt] = *reinterpret_cast<const bf16x8*>(
                &As[row * 40 + ((quad ^ ((row >> 3) & 3)) * 8)]);
        }
        #pragma unroll
        for (int nt = 0; nt < 4; nt++) {
            int col = wn * 64 + nt * 16 + lo;
            bfr[nt] = *reinterpret_cast<const bf16x8*>(
                &Bs[col * 40 + ((quad ^ ((col >> 3) & 3)) * 8)]);
        }
        #pragma unroll
        for (int mt = 0; mt < 4; mt++)
            #pragma unroll
            for (int nt = 0; nt < 4; nt++)
                acc[mt][nt] = __builtin_amdgcn_mfma_f32_16x16x32_bf16(
                    af[mt], bfr[nt], acc[mt][nt], 0, 0, 0);
    }
    float bv[4];
    #pragma unroll
    for (int nt = 0; nt < 4; nt++) bv[nt] = bias[n0 + wn * 64 + nt * 16 + lo];
    #pragma unroll
    for (int mt = 0; mt < 4; mt++)
        #pragma unroll
        for (int nt = 0; nt < 4; nt++) {
            int n = n0 + wn * 64 + nt * 16 + lo;
            #pragma unroll
            for (int r = 0; r < 4; r++) {
                int m = m0 + wm * 64 + mt * 16 + quad * 4 + r;
                O[m * 768 + n] = f2bf(acc[mt][nt][r] + bv[nt]);
            }
        }
}

// ---------------------------------------------------------------------------
// K3: q_win / k_win = xmean @ Wqkv[:, 0:512] + bqkv (fp32 exact)
// ---------------------------------------------------------------------------
__global__ __launch_bounds__(256) void k_winproj(
    const float* __restrict__ xmean,
    const float* __restrict__ W,
    const float* __restrict__ bias,
    float* __restrict__ qwin, float* __restrict__ kwin)
{
    __shared__ float xs[256];
    const int bp = blockIdx.x;
    const int c = threadIdx.x;
    xs[c] = xmean[bp * 256 + c];
    __syncthreads();
    float aq = 0.f, ak = 0.f;
    for (int k = 0; k < 256; k++) {
        float xv = xs[k];
        aq += xv * W[k * 768 + c];
        ak += xv * W[k * 768 + 256 + c];
    }
    qwin[bp * 256 + c] = aq + bias[c];
    kwin[bp * 256 + c] = ak + bias[256 + c];
}

// ---------------------------------------------------------------------------
// K4: routing logits + top-4, one block per (b, p)
// ---------------------------------------------------------------------------
__global__ __launch_bounds__(256) void k_route(
    const float* __restrict__ qwin, const float* __restrict__ kwin,
    int* __restrict__ ridx)
{
    __shared__ float part[49][4];
    __shared__ float lg[49];
    const int bp = blockIdx.x;
    const int b = bp / 49, p = bp % 49;
    const int t = threadIdx.x;
    if (t < 196) {
        int d = t >> 2, pr = t & 3;
        const float* qp = &qwin[(b * 49 + p) * 256];
        const float* kp = &kwin[(b * 49 + d) * 256];
        float a = 0.f;
        for (int ch = pr * 64; ch < pr * 64 + 64; ch++) a += qp[ch] * kp[ch];
        part[d][pr] = a;
    }
    __syncthreads();
    if (t < 49) lg[t] = (part[t][0] + part[t][1] + part[t][2] + part[t][3]);
    __syncthreads();
    if (t == 0) {
        unsigned long long used = 0ull;
        for (int sel = 0; sel < 4; sel++) {
            float best = -1e30f; int bi = 0;
            for (int qq = 0; qq < 49; qq++)
                if (!((used >> qq) & 1ull) && lg[qq] > best) { best = lg[qq]; bi = qq; }
            used |= (1ull << bi);
            ridx[bp * 4 + sel] = bi;
        }
    }
}

// ---------------------------------------------------------------------------
// K5: depthwise 5x5 LEPE conv on v channels -> bf16 (vectorized rewrite)
//   block = 8 same-row pixels x 32 channel-groups; weights staged in LDS fp32.
//   Lane layout pixel-fastest: 8 lanes share each weight address (broadcast).
// ---------------------------------------------------------------------------
__global__ __launch_bounds__(256) void k_lepe(
    const unsigned short* __restrict__ QKV,
    const float* __restrict__ lw, const float* __restrict__ lb,
    unsigned short* __restrict__ Olepe)
{
    __shared__ float lws[25 * 256];          // 25.6 KB
    const int t = threadIdx.x;
    #pragma unroll
    for (int i = 0; i < 25; i++) lws[i * 256 + t] = lw[i * 256 + t];

    const int pl = t & 7;                    // pixel within block (same image row)
    const int cg = t >> 3;                   // 0..31
    const int c0 = cg * 8;
    const int gid = blockIdx.x * 8 + pl;     // 0..12543 (56%8==0: y,b uniform per block)
    const int b = gid / 3136, rem = gid % 3136;
    const int y = rem / 56, x = rem % 56;
    __syncthreads();

    float acc[8];
    {
        float4 b0 = *reinterpret_cast<const float4*>(lb + c0);
        float4 b1 = *reinterpret_cast<const float4*>(lb + c0 + 4);
        acc[0] = b0.x; acc[1] = b0.y; acc[2] = b0.z; acc[3] = b0.w;
        acc[4] = b1.x; acc[5] = b1.y; acc[6] = b1.z; acc[7] = b1.w;
    }
    #pragma unroll
    for (int ky = 0; ky < 5; ky++) {
        int yy = y + ky - 2;
        if (yy < 0 || yy >= 56) continue;     // uniform per block
        #pragma unroll
        for (int kx = 0; kx < 5; kx++) {
            int xx = x + kx - 2;
            if (xx < 0 || xx >= 56) continue; // divergent only at image edge
            bf16x8 v = *reinterpret_cast<const bf16x8*>(
                QKV + (((b * 56) + yy) * 56 + xx) * 768 + 512 + c0);
            const float* wrow = &lws[(ky * 5 + kx) * 256 + c0];
            float4 w0 = *reinterpret_cast<const float4*>(wrow);
            float4 w1 = *reinterpret_cast<const float4*>(wrow + 4);
            acc[0] += bf2f((unsigned short)v[0]) * w0.x;
            acc[1] += bf2f((unsigned short)v[1]) * w0.y;
            acc[2] += bf2f((unsigned short)v[2]) * w0.z;
            acc[3] += bf2f((unsigned short)v[3]) * w0.w;
            acc[4] += bf2f((unsigned short)v[4]) * w1.x;
            acc[5] += bf2f((unsigned short)v[5]) * w1.y;
            acc[6] += bf2f((unsigned short)v[6]) * w1.z;
            acc[7] += bf2f((unsigned short)v[7]) * w1.w;
        }
    }
    bf16x8 o;
    #pragma unroll
    for (int j = 0; j < 8; j++) o[j] = (short)f2bf(acc[j]);
    *reinterpret_cast<bf16x8*>(Olepe + (size_t)gid * 256 + c0) = o;
}

// ---------------------------------------------------------------------------
// K6: MFMA gathered window attention; block = (p, head, b), 4 waves.
// ---------------------------------------------------------------------------
__global__ __launch_bounds__(256) void k_attn(
    const unsigned short* __restrict__ QKV,
    const int* __restrict__ ridx,
    unsigned short* __restrict__ Oattn)
{
    __shared__ __align__(16) unsigned char smem[50688];
    unsigned short* Vt = (unsigned short*)smem;                  // [32][264]
    unsigned short* Qs = (unsigned short*)(smem + 16896);        // [64][40]
    unsigned short* Ks = (unsigned short*)(smem + 22016);        // [256][40]
    unsigned short* Ps = (unsigned short*)(smem + 16896);        // 4 x [16][264] (over Qs/Ks)

    const int p = blockIdx.x, head = blockIdx.y, b = blockIdx.z;
    const int t = threadIdx.x;
    const int wi = p / 7, wj = p % 7;
    const int wave = t >> 6, lane = t & 63, quad = lane >> 4, lo = lane & 15;
    const int pix4 = t >> 2, c4 = t & 3;          // 4 lanes per pixel, 64 pixels/pass

    // ---- load Q (64 pix x 32 ch) ----
    {
        int y = wi * 8 + (pix4 >> 3), x = wj * 8 + (pix4 & 7);
        const unsigned short* qp = QKV + (((b * 56) + y) * 56 + x) * 768 + head * 32 + c4 * 8;
        bf16x8 v = *reinterpret_cast<const bf16x8*>(qp);
        int sw = c4 ^ ((pix4 >> 3) & 3);
        *reinterpret_cast<bf16x8*>(&Qs[pix4 * 40 + sw * 8]) = v;
    }
    // ---- load gathered K (row-major) and V (transposed) ----
    #pragma unroll
    for (int pass = 0; pass < 4; pass++) {
        int sel = ridx[(b * 49 + p) * 4 + pass];
        int si = sel / 7, sj = sel % 7;
        int y = si * 8 + (pix4 >> 3), x = sj * 8 + (pix4 & 7);
        const unsigned short* base = QKV + (((b * 56) + y) * 56 + x) * 768 + 256 + head * 32;
        bf16x8 kv = *reinterpret_cast<const bf16x8*>(base + c4 * 8);
        bf16x8 vv = *reinterpret_cast<const bf16x8*>(base + 256 + c4 * 8);
        int krow = pass * 64 + pix4;
        int sw = c4 ^ ((krow >> 3) & 3);
        *reinterpret_cast<bf16x8*>(&Ks[krow * 40 + sw * 8]) = kv;
        #pragma unroll
        for (int j = 0; j < 8; j++)
            Vt[(c4 * 8 + j) * 264 + krow] = (unsigned short)vv[j];
    }
    __syncthreads();

    // ---- QK^T: wave handles q rows wave*16..+15 vs all 256 keys ----
    f32x4 sc[16];
    {
        int row = wave * 16 + lo;
        bf16x8 af = *reinterpret_cast<const bf16x8*>(
            &Qs[row * 40 + ((quad ^ ((row >> 3) & 3)) * 8)]);
        f32x4 z = (f32x4){0.f, 0.f, 0.f, 0.f};
        #pragma unroll
        for (int nt = 0; nt < 16; nt++) {
            int key = nt * 16 + lo;
            bf16x8 bfr = *reinterpret_cast<const bf16x8*>(
                &Ks[key * 40 + ((quad ^ ((key >> 3) & 3)) * 8)]);
            sc[nt] = __builtin_amdgcn_mfma_f32_16x16x32_bf16(af, bfr, z, 0, 0, 0);
        }
    }
    // ---- softmax over 256 keys per q-row ----
    float M[4] = {-1e30f, -1e30f, -1e30f, -1e30f};
    #pragma unroll
    for (int nt = 0; nt < 16; nt++)
        #pragma unroll
        for (int r = 0; r < 4; r++) M[r] = fmaxf(M[r], sc[nt][r] * 0.0625f);
    #pragma unroll
    for (int d = 1; d < 16; d <<= 1)
        #pragma unroll
        for (int r = 0; r < 4; r++) M[r] = fmaxf(M[r], __shfl_xor(M[r], d));
    float l[4] = {0.f, 0.f, 0.f, 0.f};
    #pragma unroll
    for (int nt = 0; nt < 16; nt++)
        #pragma unroll
        for (int r = 0; r < 4; r++) {
            float e = __expf(sc[nt][r] * 0.0625f - M[r]);
            sc[nt][r] = e;
            l[r] += e;
        }
    #pragma unroll
    for (int d = 1; d < 16; d <<= 1)
        #pragma unroll
        for (int r = 0; r < 4; r++) l[r] += __shfl_xor(l[r], d);

    __syncthreads();   // all waves done reading Qs/Ks -> Ps may overwrite

    // ---- write P (bf16) to this wave's LDS tile [16][264] ----
    // (no barrier needed after: PV reads only this wave's own tile; compiler
    //  inserts the lgkmcnt waits for intra-wave LDS dependencies)
    unsigned short* myPs = Ps + wave * 16 * 264;
    #pragma unroll
    for (int nt = 0; nt < 16; nt++)
        #pragma unroll
        for (int r = 0; r < 4; r++)
            myPs[(quad * 4 + r) * 264 + nt * 16 + lo] = f2bf(sc[nt][r]);

    // ---- PV: O[16 q x 32 d] = P[16x256] @ V[256x32], via Vt[d][key] ----
    f32x4 o0 = (f32x4){0.f, 0.f, 0.f, 0.f}, o1 = o0;
    #pragma unroll
    for (int kt = 0; kt < 8; kt++) {
        bf16x8 pa = *reinterpret_cast<const bf16x8*>(
            &myPs[lo * 264 + kt * 32 + quad * 8]);
        bf16x8 vb0 = *reinterpret_cast<const bf16x8*>(
            &Vt[lo * 264 + kt * 32 + quad * 8]);
        bf16x8 vb1 = *reinterpret_cast<const bf16x8*>(
            &Vt[(16 + lo) * 264 + kt * 32 + quad * 8]);
        o0 = __builtin_amdgcn_mfma_f32_16x16x32_bf16(pa, vb0, o0, 0, 0, 0);
        o1 = __builtin_amdgcn_mfma_f32_16x16x32_bf16(pa, vb1, o1, 0, 0, 0);
    }
    // ---- epilogue: divide by L, store bf16 to image layout ----
    #pragma unroll
    for (int r = 0; r < 4; r++) {
        int q = wave * 16 + quad * 4 + r;
        int y = wi * 8 + (q >> 3), x = wj * 8 + (q & 7);
        unsigned short* op = Oattn + (((b * 56) + y) * 56 + x) * 256 + head * 32;
        float inv = 1.0f / l[r];
        op[lo]      = f2bf(o0[r] * inv);
        op[16 + lo] = f2bf(o1[r] * inv);
    }
}

// ---------------------------------------------------------------------------
// K7: out proj (MFMA): (Oattn+Olepe)[12544,256] @ Wo[256,256] + bo -> fp32 out
// ---------------------------------------------------------------------------
__global__ __launch_bounds__(256) void k_proj(
    const unsigned short* __restrict__ A1, const unsigned short* __restrict__ A2,
    const unsigned short* __restrict__ Bt,   // Wto [256][256] (= Wo^T)
    const float* __restrict__ bias,
    float* __restrict__ O)
{
    __shared__ unsigned short As[128 * 40];
    __shared__ unsigned short Bs[64 * 40];
    const int t = threadIdx.x;
    const int m0 = blockIdx.x * 128, n0 = blockIdx.y * 64;
    const int wave = t >> 6, lane = t & 63, quad = lane >> 4, lo = lane & 15;
    const int srow = t >> 1, sh = t & 1;     // A staging
    const int brow = t >> 2, bc = t & 3;     // B staging
    f32x4 acc[2][4];
    #pragma unroll
    for (int i = 0; i < 2; i++)
        #pragma unroll
        for (int j = 0; j < 4; j++) acc[i][j] = (f32x4){0.f, 0.f, 0.f, 0.f};

    for (int kt = 0; kt < 256; kt += 32) {
        const unsigned short* a1g = A1 + (m0 + srow) * 256 + kt + sh * 16;
        const unsigned short* a2g = A2 + (m0 + srow) * 256 + kt + sh * 16;
        bf16x8 x0 = *reinterpret_cast<const bf16x8*>(a1g);
        bf16x8 x1 = *reinterpret_cast<const bf16x8*>(a1g + 8);
        bf16x8 y0 = *reinterpret_cast<const bf16x8*>(a2g);
        bf16x8 y1 = *reinterpret_cast<const bf16x8*>(a2g + 8);
        bf16x8 bgv = *reinterpret_cast<const bf16x8*>(
            Bt + (n0 + brow) * 256 + kt + bc * 8);
        bf16x8 s0, s1;
        #pragma unroll
        for (int j = 0; j < 8; j++) {
            s0[j] = (short)f2bf(bf2f((unsigned short)x0[j]) + bf2f((unsigned short)y0[j]));
            s1[j] = (short)f2bf(bf2f((unsigned short)x1[j]) + bf2f((unsigned short)y1[j]));
        }
        int g  = (srow >> 3) & 3;
        int c0 = (sh * 2) ^ g, c1 = (sh * 2 + 1) ^ g;
        int gb = (brow >> 3) & 3;
        __syncthreads();
        *reinterpret_cast<bf16x8*>(&As[srow * 40 + c0 * 8]) = s0;
        *reinterpret_cast<bf16x8*>(&As[srow * 40 + c1 * 8]) = s1;
        *reinterpret_cast<bf16x8*>(&Bs[brow * 40 + ((bc ^ gb) * 8)]) = bgv;
        __syncthreads();
        bf16x8 af[2], bfr[4];
        #pragma unroll
        for (int mt = 0; mt < 2; mt++) {
            int row = wave * 32 + mt * 16 + lo;
            af[mt] = *reinterpret_cast<const bf16x8*>(
                &As[row * 40 + ((quad ^ ((row >> 3) & 3)) * 8)]);
        }
        #pragma unroll
        for (int nt = 0; nt < 4; nt++) {
            int col = nt * 16 + lo;
            bfr[nt] = *reinterpret_cast<const bf16x8*>(
                &Bs[col * 40 + ((quad ^ ((col >> 3) & 3)) * 8)]);
        }
        #pragma unroll
        for (int mt = 0; mt < 2; mt++)
            #pragma unroll
            for (int nt = 0; nt < 4; nt++)
                acc[mt][nt] = __builtin_amdgcn_mfma_f32_16x16x32_bf16(
                    af[mt], bfr[nt], acc[mt][nt], 0, 0, 0);
    }
    float bv[4];
    #pragma unroll
    for (int nt = 0; nt < 4; nt++) bv[nt] = bias[n0 + nt * 16 + lo];
    #pragma unroll
    for (int mt = 0; mt < 2; mt++)
        #pragma unroll
        for (int nt = 0; nt < 4; nt++) {
            int n = n0 + nt * 16 + lo;
            #pragma unroll
            for (int r = 0; r < 4; r++) {
                int m = m0 + wave * 32 + mt * 16 + quad * 4 + r;
                O[m * 256 + n] = acc[mt][nt][r] + bv[nt];
            }
        }
}

// ---------------------------------------------------------------------------
extern "C" void kernel_launch(void* const* d_in, const int* in_sizes, int n_in,
                              void* d_out, int out_size, void* d_ws, size_t ws_size,
                              hipStream_t stream)
{
    const float* x    = (const float*)d_in[0];
    const float* Wqkv = (const float*)d_in[1];
    const float* bqkv = (const float*)d_in[2];
    const float* Wo   = (const float*)d_in[3];
    const float* bo   = (const float*)d_in[4];
    const float* lw   = (const float*)d_in[5];
    const float* lb   = (const float*)d_in[6];
    float* out = (float*)d_out;

    char* ws = (char*)d_ws;
    size_t off = 0;
    unsigned short* qkv   = (unsigned short*)(ws + off); off += (size_t)NPIX * 768 * 2;
    unsigned short* xb    = (unsigned short*)(ws + off); off += (size_t)NPIX * 256 * 2;
    unsigned short* Wtq   = (unsigned short*)(ws + off); off += 768 * 256 * 2;
    unsigned short* Wto   = (unsigned short*)(ws + off); off += 256 * 256 * 2;
    unsigned short* Oattn = (unsigned short*)(ws + off); off += (size_t)NPIX * 256 * 2;
    unsigned short* Olepe = (unsigned short*)(ws + off); off += (size_t)NPIX * 256 * 2;
    float* xmean = (float*)(ws + off); off += 196 * 256 * 4;
    float* qwin  = (float*)(ws + off); off += 196 * 256 * 4;
    float* kwin  = (float*)(ws + off); off += 196 * 256 * 4;
    int*   ridx  = (int*)(ws + off);   off += 196 * 4 * 4;

    k_prep_x  <<<dim3(196),      256, 0, stream>>>(x, xb, xmean);
    k_cvt_w   <<<dim3(1024),     256, 0, stream>>>(Wqkv, Wo, Wtq, Wto);
    k_qkv_gemm<<<dim3(98, 6),    256, 0, stream>>>(xb, Wtq, bqkv, qkv);
    k_winproj <<<dim3(196),      256, 0, stream>>>(xmean, Wqkv, bqkv, qwin, kwin);
    k_route   <<<dim3(196),      256, 0, stream>>>(qwin, kwin, ridx);
    k_lepe    <<<dim3(1568),     256, 0, stream>>>(qkv, lw, lb, Olepe);
    k_attn    <<<dim3(49, 8, 4), 256, 0, stream>>>(qkv, ridx, Oattn);
    k_proj    <<<dim3(98, 4),    256, 0, stream>>>(Oattn, Olepe, Wto, bo, out);
}

// Round 6
// 172.471 us; speedup vs baseline: 3.3833x; 1.0489x over previous
//
#include <hip/hip_runtime.h>
#include <hip/hip_bf16.h>

// B=4, H=W=56, C=256, 7x7 windows of 8x8, 8 heads x 32, top-4.
// Inputs fp32; d_out fp32. Intermediates bf16; MFMA bf16 w/ fp32 accum.
#define NPIX 12544   // B*56*56

typedef short bf16x8 __attribute__((ext_vector_type(8)));
typedef float f32x4  __attribute__((ext_vector_type(4)));

__device__ __forceinline__ float bf2f(unsigned short u) {
    unsigned int x = ((unsigned int)u) << 16;
    float f; __builtin_memcpy(&f, &x, sizeof(f)); return f;
}
__device__ __forceinline__ unsigned short f2bf(float f) {
    __hip_bfloat16 h = __float2bfloat16(f);
    unsigned short u; __builtin_memcpy(&u, &h, 2); return u;
}

// ---------------------------------------------------------------------------
// K0: fused prep.
//   blocks 0..195   : x -> bf16 + per-window mean (float4 loads, LDS reduce)
//   blocks 196..243 : Wqkv^T tiles (64x64 LDS transpose, coalesced R/W)
//   blocks 244..259 : Wo^T tiles
// ---------------------------------------------------------------------------
__global__ __launch_bounds__(256) void k_prep(
    const float* __restrict__ X, unsigned short* __restrict__ Xb,
    float* __restrict__ xmean,
    const float* __restrict__ Wqkv, const float* __restrict__ Wo,
    unsigned short* __restrict__ Wtq, unsigned short* __restrict__ Wto)
{
    __shared__ __align__(16) unsigned char sm[64 * 65 * 4];   // 16.6 KB union
    const int t = threadIdx.x;
    const int blk = blockIdx.x;
    if (blk < 196) {
        float* part = (float*)sm;                 // [4 slots][64 cg][4]
        const int b = blk / 49, p = blk % 49;
        const int wi = p / 7, wj = p % 7;
        const int ps = t >> 6, cg = t & 63;
        float4 s = {0.f, 0.f, 0.f, 0.f};
        #pragma unroll
        for (int i = 0; i < 16; i++) {
            int pp = ps * 16 + i;
            int y = wi * 8 + (pp >> 3), x = wj * 8 + (pp & 7);
            int idx = (((b * 56) + y) * 56 + x) * 256 + cg * 4;
            float4 v = *reinterpret_cast<const float4*>(X + idx);
            s.x += v.x; s.y += v.y; s.z += v.z; s.w += v.w;
            ushort4 o = { f2bf(v.x), f2bf(v.y), f2bf(v.z), f2bf(v.w) };
            *reinterpret_cast<ushort4*>(Xb + idx) = o;
        }
        *reinterpret_cast<float4*>(part + t * 4) = *reinterpret_cast<float4*>(&s);
        __syncthreads();
        if (t < 64) {
            float4 a = *reinterpret_cast<float4*>(part + t * 4);
            float4 b2 = *reinterpret_cast<float4*>(part + (64 + t) * 4);
            float4 c = *reinterpret_cast<float4*>(part + (128 + t) * 4);
            float4 d = *reinterpret_cast<float4*>(part + (192 + t) * 4);
            float4 m = { (a.x + b2.x + c.x + d.x) * (1.f / 64.f),
                         (a.y + b2.y + c.y + d.y) * (1.f / 64.f),
                         (a.z + b2.z + c.z + d.z) * (1.f / 64.f),
                         (a.w + b2.w + c.w + d.w) * (1.f / 64.f) };
            *reinterpret_cast<float4*>(xmean + blk * 256 + t * 4) = m;
        }
    } else {
        float* tile = (float*)sm;                 // [64][65]
        int tb = blk - 196;
        const float* Wsrc; unsigned short* Wdst; int N, kt, nt;
        if (tb < 48) { Wsrc = Wqkv; Wdst = Wtq; N = 768; kt = tb / 12; nt = tb % 12; }
        else { tb -= 48; Wsrc = Wo; Wdst = Wto; N = 256; kt = tb / 4; nt = tb % 4; }
        const int k0 = kt * 64, n0 = nt * 64;
        const int r0 = t >> 6, c = t & 63;
        #pragma unroll
        for (int i = 0; i < 16; i++) {
            int r = i * 4 + r0;
            tile[r * 65 + c] = Wsrc[(size_t)(k0 + r) * N + n0 + c];
        }
        __syncthreads();
        #pragma unroll
        for (int i = 0; i < 16; i++) {
            int n = i * 4 + r0;
            Wdst[(size_t)(n0 + n) * 256 + k0 + c] = f2bf(tile[c * 65 + n]);
        }
    }
}

// ---------------------------------------------------------------------------
// K1: qkv GEMM (MFMA)  xb[12544,256] @ Wqkv[256,768] + bqkv -> qkv bf16
// ---------------------------------------------------------------------------
__global__ __launch_bounds__(256) void k_qkv_gemm(
    const unsigned short* __restrict__ A,   // xb [12544][256]
    const unsigned short* __restrict__ Bt,  // Wtq [768][256]
    const float* __restrict__ bias,
    unsigned short* __restrict__ O)
{
    __shared__ unsigned short As[128 * 40];
    __shared__ unsigned short Bs[128 * 40];
    const int t = threadIdx.x;
    const int m0 = blockIdx.x * 128, n0 = blockIdx.y * 128;
    const int wave = t >> 6, lane = t & 63, quad = lane >> 4, lo = lane & 15;
    const int wm = wave & 1, wn = wave >> 1;
    const int srow = t >> 1, sh = t & 1;
    f32x4 acc[4][4];
    #pragma unroll
    for (int i = 0; i < 4; i++)
        #pragma unroll
        for (int j = 0; j < 4; j++) acc[i][j] = (f32x4){0.f, 0.f, 0.f, 0.f};

    for (int kt = 0; kt < 256; kt += 32) {
        const unsigned short* ag = A  + (m0 + srow) * 256 + kt + sh * 16;
        const unsigned short* bg = Bt + (n0 + srow) * 256 + kt + sh * 16;
        bf16x8 a0 = *reinterpret_cast<const bf16x8*>(ag);
        bf16x8 a1 = *reinterpret_cast<const bf16x8*>(ag + 8);
        bf16x8 b0 = *reinterpret_cast<const bf16x8*>(bg);
        bf16x8 b1 = *reinterpret_cast<const bf16x8*>(bg + 8);
        int g  = (srow >> 3) & 3;
        int c0 = (sh * 2) ^ g, c1 = (sh * 2 + 1) ^ g;
        __syncthreads();
        *reinterpret_cast<bf16x8*>(&As[srow * 40 + c0 * 8]) = a0;
        *reinterpret_cast<bf16x8*>(&As[srow * 40 + c1 * 8]) = a1;
        *reinterpret_cast<bf16x8*>(&Bs[srow * 40 + c0 * 8]) = b0;
        *reinterpret_cast<bf16x8*>(&Bs[srow * 40 + c1 * 8]) = b1;
        __syncthreads();
        bf16x8 af[4], bfr[4];
        #pragma unroll
        for (int mt = 0; mt < 4; mt++) {
            int row = wm * 64 + mt * 16 + lo;
            af[mt] = *reinterpret_cast<const bf16x8*>(
                &As[row * 40 + ((quad ^ ((row >> 3) & 3)) * 8)]);
        }
        #pragma unroll
        for (int nt = 0; nt < 4; nt++) {
            int col = wn * 64 + nt * 16 + lo;
            bfr[nt] = *reinterpret_cast<const bf16x8*>(
                &Bs[col * 40 + ((quad ^ ((col >> 3) & 3)) * 8)]);
        }
        #pragma unroll
        for (int mt = 0; mt < 4; mt++)
            #pragma unroll
            for (int nt = 0; nt < 4; nt++)
                acc[mt][nt] = __builtin_amdgcn_mfma_f32_16x16x32_bf16(
                    af[mt], bfr[nt], acc[mt][nt], 0, 0, 0);
    }
    float bv[4];
    #pragma unroll
    for (int nt = 0; nt < 4; nt++) bv[nt] = bias[n0 + wn * 64 + nt * 16 + lo];
    #pragma unroll
    for (int mt = 0; mt < 4; mt++)
        #pragma unroll
        for (int nt = 0; nt < 4; nt++) {
            int n = n0 + wn * 64 + nt * 16 + lo;
            #pragma unroll
            for (int r = 0; r < 4; r++) {
                int m = m0 + wm * 64 + mt * 16 + quad * 4 + r;
                O[m * 768 + n] = f2bf(acc[mt][nt][r] + bv[nt]);
            }
        }
}

// ---------------------------------------------------------------------------
// K3: winproj, split q/k across blockIdx.y (392 blocks)
// ---------------------------------------------------------------------------
__global__ __launch_bounds__(256) void k_winproj(
    const float* __restrict__ xmean,
    const float* __restrict__ W,
    const float* __restrict__ bias,
    float* __restrict__ qwin, float* __restrict__ kwin)
{
    __shared__ float xs[256];
    const int bp = blockIdx.x;
    const int half = blockIdx.y;          // 0 -> qwin, 1 -> kwin
    const int c = threadIdx.x;
    xs[c] = xmean[bp * 256 + c];
    __syncthreads();
    const int col = half * 256 + c;
    float a = 0.f;
    for (int k = 0; k < 256; k++) a += xs[k] * W[k * 768 + col];
    float* outp = half ? kwin : qwin;
    outp[bp * 256 + c] = a + bias[col];
}

// ---------------------------------------------------------------------------
// K4: routing logits + top-4, one block per (b, p)
// ---------------------------------------------------------------------------
__global__ __launch_bounds__(256) void k_route(
    const float* __restrict__ qwin, const float* __restrict__ kwin,
    int* __restrict__ ridx)
{
    __shared__ float part[49][4];
    __shared__ float lg[49];
    const int bp = blockIdx.x;
    const int b = bp / 49, p = bp % 49;
    const int t = threadIdx.x;
    if (t < 196) {
        int d = t >> 2, pr = t & 3;
        const float* qp = &qwin[(b * 49 + p) * 256];
        const float* kp = &kwin[(b * 49 + d) * 256];
        float a = 0.f;
        for (int ch = pr * 64; ch < pr * 64 + 64; ch++) a += qp[ch] * kp[ch];
        part[d][pr] = a;
    }
    __syncthreads();
    if (t < 49) lg[t] = (part[t][0] + part[t][1] + part[t][2] + part[t][3]);
    __syncthreads();
    if (t == 0) {
        unsigned long long used = 0ull;
        for (int sel = 0; sel < 4; sel++) {
            float best = -1e30f; int bi = 0;
            for (int qq = 0; qq < 49; qq++)
                if (!((used >> qq) & 1ull) && lg[qq] > best) { best = lg[qq]; bi = qq; }
            used |= (1ull << bi);
            ridx[bp * 4 + sel] = bi;
        }
    }
}

// ---------------------------------------------------------------------------
// K5: depthwise 5x5 LEPE conv on v channels -> bf16
// ---------------------------------------------------------------------------
__global__ __launch_bounds__(256) void k_lepe(
    const unsigned short* __restrict__ QKV,
    const float* __restrict__ lw, const float* __restrict__ lb,
    unsigned short* __restrict__ Olepe)
{
    __shared__ float lws[25 * 256];
    const int t = threadIdx.x;
    #pragma unroll
    for (int i = 0; i < 25; i++) lws[i * 256 + t] = lw[i * 256 + t];

    const int pl = t & 7;
    const int cg = t >> 3;
    const int c0 = cg * 8;
    const int gid = blockIdx.x * 8 + pl;
    const int b = gid / 3136, rem = gid % 3136;
    const int y = rem / 56, x = rem % 56;
    __syncthreads();

    float acc[8];
    {
        float4 b0 = *reinterpret_cast<const float4*>(lb + c0);
        float4 b1 = *reinterpret_cast<const float4*>(lb + c0 + 4);
        acc[0] = b0.x; acc[1] = b0.y; acc[2] = b0.z; acc[3] = b0.w;
        acc[4] = b1.x; acc[5] = b1.y; acc[6] = b1.z; acc[7] = b1.w;
    }
    #pragma unroll
    for (int ky = 0; ky < 5; ky++) {
        int yy = y + ky - 2;
        if (yy < 0 || yy >= 56) continue;
        #pragma unroll
        for (int kx = 0; kx < 5; kx++) {
            int xx = x + kx - 2;
            if (xx < 0 || xx >= 56) continue;
            bf16x8 v = *reinterpret_cast<const bf16x8*>(
                QKV + (((b * 56) + yy) * 56 + xx) * 768 + 512 + c0);
            const float* wrow = &lws[(ky * 5 + kx) * 256 + c0];
            float4 w0 = *reinterpret_cast<const float4*>(wrow);
            float4 w1 = *reinterpret_cast<const float4*>(wrow + 4);
            acc[0] += bf2f((unsigned short)v[0]) * w0.x;
            acc[1] += bf2f((unsigned short)v[1]) * w0.y;
            acc[2] += bf2f((unsigned short)v[2]) * w0.z;
            acc[3] += bf2f((unsigned short)v[3]) * w0.w;
            acc[4] += bf2f((unsigned short)v[4]) * w1.x;
            acc[5] += bf2f((unsigned short)v[5]) * w1.y;
            acc[6] += bf2f((unsigned short)v[6]) * w1.z;
            acc[7] += bf2f((unsigned short)v[7]) * w1.w;
        }
    }
    bf16x8 o;
    #pragma unroll
    for (int j = 0; j < 8; j++) o[j] = (short)f2bf(acc[j]);
    *reinterpret_cast<bf16x8*>(Olepe + (size_t)gid * 256 + c0) = o;
}

// ---------------------------------------------------------------------------
// K6: MFMA gathered window attention + fused "+lepe" epilogue -> Osum
// ---------------------------------------------------------------------------
__global__ __launch_bounds__(256) void k_attn(
    const unsigned short* __restrict__ QKV,
    const int* __restrict__ ridx,
    const unsigned short* __restrict__ Olepe,
    unsigned short* __restrict__ Osum)
{
    __shared__ __align__(16) unsigned char smem[50688];
    unsigned short* Vt = (unsigned short*)smem;                  // [32][264]
    unsigned short* Qs = (unsigned short*)(smem + 16896);        // [64][40]
    unsigned short* Ks = (unsigned short*)(smem + 22016);        // [256][40]
    unsigned short* Ps = (unsigned short*)(smem + 16896);        // 4 x [16][264]

    const int p = blockIdx.x, head = blockIdx.y, b = blockIdx.z;
    const int t = threadIdx.x;
    const int wi = p / 7, wj = p % 7;
    const int wave = t >> 6, lane = t & 63, quad = lane >> 4, lo = lane & 15;
    const int pix4 = t >> 2, c4 = t & 3;

    {
        int y = wi * 8 + (pix4 >> 3), x = wj * 8 + (pix4 & 7);
        const unsigned short* qp = QKV + (((b * 56) + y) * 56 + x) * 768 + head * 32 + c4 * 8;
        bf16x8 v = *reinterpret_cast<const bf16x8*>(qp);
        int sw = c4 ^ ((pix4 >> 3) & 3);
        *reinterpret_cast<bf16x8*>(&Qs[pix4 * 40 + sw * 8]) = v;
    }
    #pragma unroll
    for (int pass = 0; pass < 4; pass++) {
        int sel = ridx[(b * 49 + p) * 4 + pass];
        int si = sel / 7, sj = sel % 7;
        int y = si * 8 + (pix4 >> 3), x = sj * 8 + (pix4 & 7);
        const unsigned short* base = QKV + (((b * 56) + y) * 56 + x) * 768 + 256 + head * 32;
        bf16x8 kv = *reinterpret_cast<const bf16x8*>(base + c4 * 8);
        bf16x8 vv = *reinterpret_cast<const bf16x8*>(base + 256 + c4 * 8);
        int krow = pass * 64 + pix4;
        int sw = c4 ^ ((krow >> 3) & 3);
        *reinterpret_cast<bf16x8*>(&Ks[krow * 40 + sw * 8]) = kv;
        #pragma unroll
        for (int j = 0; j < 8; j++)
            Vt[(c4 * 8 + j) * 264 + krow] = (unsigned short)vv[j];
    }
    __syncthreads();

    f32x4 sc[16];
    {
        int row = wave * 16 + lo;
        bf16x8 af = *reinterpret_cast<const bf16x8*>(
            &Qs[row * 40 + ((quad ^ ((row >> 3) & 3)) * 8)]);
        f32x4 z = (f32x4){0.f, 0.f, 0.f, 0.f};
        #pragma unroll
        for (int nt = 0; nt < 16; nt++) {
            int key = nt * 16 + lo;
            bf16x8 bfr = *reinterpret_cast<const bf16x8*>(
                &Ks[key * 40 + ((quad ^ ((key >> 3) & 3)) * 8)]);
            sc[nt] = __builtin_amdgcn_mfma_f32_16x16x32_bf16(af, bfr, z, 0, 0, 0);
        }
    }
    float M[4] = {-1e30f, -1e30f, -1e30f, -1e30f};
    #pragma unroll
    for (int nt = 0; nt < 16; nt++)
        #pragma unroll
        for (int r = 0; r < 4; r++) M[r] = fmaxf(M[r], sc[nt][r] * 0.0625f);
    #pragma unroll
    for (int d = 1; d < 16; d <<= 1)
        #pragma unroll
        for (int r = 0; r < 4; r++) M[r] = fmaxf(M[r], __shfl_xor(M[r], d));
    float l[4] = {0.f, 0.f, 0.f, 0.f};
    #pragma unroll
    for (int nt = 0; nt < 16; nt++)
        #pragma unroll
        for (int r = 0; r < 4; r++) {
            float e = __expf(sc[nt][r] * 0.0625f - M[r]);
            sc[nt][r] = e;
            l[r] += e;
        }
    #pragma unroll
    for (int d = 1; d < 16; d <<= 1)
        #pragma unroll
        for (int r = 0; r < 4; r++) l[r] += __shfl_xor(l[r], d);

    __syncthreads();   // all waves done reading Qs/Ks -> Ps may overwrite

    unsigned short* myPs = Ps + wave * 16 * 264;
    #pragma unroll
    for (int nt = 0; nt < 16; nt++)
        #pragma unroll
        for (int r = 0; r < 4; r++)
            myPs[(quad * 4 + r) * 264 + nt * 16 + lo] = f2bf(sc[nt][r]);

    f32x4 o0 = (f32x4){0.f, 0.f, 0.f, 0.f}, o1 = o0;
    #pragma unroll
    for (int kt = 0; kt < 8; kt++) {
        bf16x8 pa = *reinterpret_cast<const bf16x8*>(
            &myPs[lo * 264 + kt * 32 + quad * 8]);
        bf16x8 vb0 = *reinterpret_cast<const bf16x8*>(
            &Vt[lo * 264 + kt * 32 + quad * 8]);
        bf16x8 vb1 = *reinterpret_cast<const bf16x8*>(
            &Vt[(16 + lo) * 264 + kt * 32 + quad * 8]);
        o0 = __builtin_amdgcn_mfma_f32_16x16x32_bf16(pa, vb0, o0, 0, 0, 0);
        o1 = __builtin_amdgcn_mfma_f32_16x16x32_bf16(pa, vb1, o1, 0, 0, 0);
    }
    #pragma unroll
    for (int r = 0; r < 4; r++) {
        int q = wave * 16 + quad * 4 + r;
        int y = wi * 8 + (q >> 3), x = wj * 8 + (q & 7);
        size_t base = (size_t)(((b * 56) + y) * 56 + x) * 256 + head * 32;
        const unsigned short* lp = Olepe + base;
        unsigned short* op = Osum + base;
        float inv = 1.0f / l[r];
        op[lo]      = f2bf(o0[r] * inv + bf2f(lp[lo]));
        op[16 + lo] = f2bf(o1[r] * inv + bf2f(lp[16 + lo]));
    }
}

// ---------------------------------------------------------------------------
// K7: out proj (MFMA): Osum[12544,256] @ Wo[256,256] + bo -> fp32 out
// ---------------------------------------------------------------------------
__global__ __launch_bounds__(256) void k_proj(
    const unsigned short* __restrict__ A,
    const unsigned short* __restrict__ Bt,   // Wto [256][256]
    const float* __restrict__ bias,
    float* __restrict__ O)
{
    __shared__ unsigned short As[128 * 40];
    __shared__ unsigned short Bs[64 * 40];
    const int t = threadIdx.x;
    const int m0 = blockIdx.x * 128, n0 = blockIdx.y * 64;
    const int wave = t >> 6, lane = t & 63, quad = lane >> 4, lo = lane & 15;
    const int srow = t >> 1, sh = t & 1;
    const int brow = t >> 2, bc = t & 3;
    f32x4 acc[2][4];
    #pragma unroll
    for (int i = 0; i < 2; i++)
        #pragma unroll
        for (int j = 0; j < 4; j++) acc[i][j] = (f32x4){0.f, 0.f, 0.f, 0.f};

    for (int kt = 0; kt < 256; kt += 32) {
        const unsigned short* ag = A + (m0 + srow) * 256 + kt + sh * 16;
        bf16x8 x0 = *reinterpret_cast<const bf16x8*>(ag);
        bf16x8 x1 = *reinterpret_cast<const bf16x8*>(ag + 8);
        bf16x8 bgv = *reinterpret_cast<const bf16x8*>(
            Bt + (n0 + brow) * 256 + kt + bc * 8);
        int g  = (srow >> 3) & 3;
        int c0 = (sh * 2) ^ g, c1 = (sh * 2 + 1) ^ g;
        int gb = (brow >> 3) & 3;
        __syncthreads();
        *reinterpret_cast<bf16x8*>(&As[srow * 40 + c0 * 8]) = x0;
        *reinterpret_cast<bf16x8*>(&As[srow * 40 + c1 * 8]) = x1;
        *reinterpret_cast<bf16x8*>(&Bs[brow * 40 + ((bc ^ gb) * 8)]) = bgv;
        __syncthreads();
        bf16x8 af[2], bfr[4];
        #pragma unroll
        for (int mt = 0; mt < 2; mt++) {
            int row = wave * 32 + mt * 16 + lo;
            af[mt] = *reinterpret_cast<const bf16x8*>(
                &As[row * 40 + ((quad ^ ((row >> 3) & 3)) * 8)]);
        }
        #pragma unroll
        for (int nt = 0; nt < 4; nt++) {
            int col = nt * 16 + lo;
            bfr[nt] = *reinterpret_cast<const bf16x8*>(
                &Bs[col * 40 + ((quad ^ ((col >> 3) & 3)) * 8)]);
        }
        #pragma unroll
        for (int mt = 0; mt < 2; mt++)
            #pragma unroll
            for (int nt = 0; nt < 4; nt++)
                acc[mt][nt] = __builtin_amdgcn_mfma_f32_16x16x32_bf16(
                    af[mt], bfr[nt], acc[mt][nt], 0, 0, 0);
    }
    float bv[4];
    #pragma unroll
    for (int nt = 0; nt < 4; nt++) bv[nt] = bias[n0 + nt * 16 + lo];
    #pragma unroll
    for (int mt = 0; mt < 2; mt++)
        #pragma unroll
        for (int nt = 0; nt < 4; nt++) {
            int n = n0 + nt * 16 + lo;
            #pragma unroll
            for (int r = 0; r < 4; r++) {
                int m = m0 + wave * 32 + mt * 16 + quad * 4 + r;
                O[m * 256 + n] = acc[mt][nt][r] + bv[nt];
            }
        }
}

// ---------------------------------------------------------------------------
extern "C" void kernel_launch(void* const* d_in, const int* in_sizes, int n_in,
                              void* d_out, int out_size, void* d_ws, size_t ws_size,
                              hipStream_t stream)
{
    const float* x    = (const float*)d_in[0];
    const float* Wqkv = (const float*)d_in[1];
    const float* bqkv = (const float*)d_in[2];
    const float* Wo   = (const float*)d_in[3];
    const float* bo   = (const float*)d_in[4];
    const float* lw   = (const float*)d_in[5];
    const float* lb   = (const float*)d_in[6];
    float* out = (float*)d_out;

    char* ws = (char*)d_ws;
    size_t off = 0;
    unsigned short* qkv   = (unsigned short*)(ws + off); off += (size_t)NPIX * 768 * 2;
    unsigned short* xb    = (unsigned short*)(ws + off); off += (size_t)NPIX * 256 * 2;
    unsigned short* Wtq   = (unsigned short*)(ws + off); off += 768 * 256 * 2;
    unsigned short* Wto   = (unsigned short*)(ws + off); off += 256 * 256 * 2;
    unsigned short* Osum  = (unsigned short*)(ws + off); off += (size_t)NPIX * 256 * 2;
    unsigned short* Olepe = (unsigned short*)(ws + off); off += (size_t)NPIX * 256 * 2;
    float* xmean = (float*)(ws + off); off += 196 * 256 * 4;
    float* qwin  = (float*)(ws + off); off += 196 * 256 * 4;
    float* kwin  = (float*)(ws + off); off += 196 * 256 * 4;
    int*   ridx  = (int*)(ws + off);   off += 196 * 4 * 4;

    k_prep    <<<dim3(260),      256, 0, stream>>>(x, xb, xmean, Wqkv, Wo, Wtq, Wto);
    k_qkv_gemm<<<dim3(98, 6),    256, 0, stream>>>(xb, Wtq, bqkv, qkv);
    k_winproj <<<dim3(196, 2),   256, 0, stream>>>(xmean, Wqkv, bqkv, qwin, kwin);
    k_route   <<<dim3(196),      256, 0, stream>>>(qwin, kwin, ridx);
    k_lepe    <<<dim3(1568),     256, 0, stream>>>(qkv, lw, lb, Olepe);
    k_attn    <<<dim3(49, 8, 4), 256, 0, stream>>>(qkv, ridx, Olepe, Osum);
    k_proj    <<<dim3(98, 4),    256, 0, stream>>>(Osum, Wto, bo, out);
}

// Round 7
// 168.226 us; speedup vs baseline: 3.4687x; 1.0252x over previous
//
#include <hip/hip_runtime.h>
#include <hip/hip_bf16.h>

// B=4, H=W=56, C=256, 7x7 windows of 8x8, 8 heads x 32, top-4.
// Inputs fp32; d_out fp32. Intermediates bf16; MFMA bf16 w/ fp32 accum.
#define NPIX 12544   // B*56*56

typedef short bf16x8 __attribute__((ext_vector_type(8)));
typedef float f32x4  __attribute__((ext_vector_type(4)));

__device__ __forceinline__ float bf2f(unsigned short u) {
    unsigned int x = ((unsigned int)u) << 16;
    float f; __builtin_memcpy(&f, &x, sizeof(f)); return f;
}
__device__ __forceinline__ unsigned short f2bf(float f) {
    __hip_bfloat16 h = __float2bfloat16(f);
    unsigned short u; __builtin_memcpy(&u, &h, 2); return u;
}
// async global->LDS DMA, 16B per lane; LDS dest is wave-uniform base + lane*16
__device__ __forceinline__ void load_lds16(const unsigned short* g, unsigned short* l) {
    __builtin_amdgcn_global_load_lds(
        (const __attribute__((address_space(1))) unsigned int*)g,
        (__attribute__((address_space(3))) unsigned int*)l,
        16, 0, 0);
}

// ---------------------------------------------------------------------------
// K0: fused prep.
//   blocks 0..195   : x -> bf16 + per-window mean (float4 loads, LDS reduce)
//   blocks 196..243 : Wqkv^T tiles (64x64 LDS transpose, coalesced R/W)
//   blocks 244..259 : Wo^T tiles
// ---------------------------------------------------------------------------
__global__ __launch_bounds__(256) void k_prep(
    const float* __restrict__ X, unsigned short* __restrict__ Xb,
    float* __restrict__ xmean,
    const float* __restrict__ Wqkv, const float* __restrict__ Wo,
    unsigned short* __restrict__ Wtq, unsigned short* __restrict__ Wto)
{
    __shared__ __align__(16) unsigned char sm[64 * 65 * 4];   // 16.6 KB union
    const int t = threadIdx.x;
    const int blk = blockIdx.x;
    if (blk < 196) {
        float* part = (float*)sm;                 // [4 slots][64 cg][4]
        const int b = blk / 49, p = blk % 49;
        const int wi = p / 7, wj = p % 7;
        const int ps = t >> 6, cg = t & 63;
        float4 s = {0.f, 0.f, 0.f, 0.f};
        #pragma unroll
        for (int i = 0; i < 16; i++) {
            int pp = ps * 16 + i;
            int y = wi * 8 + (pp >> 3), x = wj * 8 + (pp & 7);
            int idx = (((b * 56) + y) * 56 + x) * 256 + cg * 4;
            float4 v = *reinterpret_cast<const float4*>(X + idx);
            s.x += v.x; s.y += v.y; s.z += v.z; s.w += v.w;
            ushort4 o = { f2bf(v.x), f2bf(v.y), f2bf(v.z), f2bf(v.w) };
            *reinterpret_cast<ushort4*>(Xb + idx) = o;
        }
        *reinterpret_cast<float4*>(part + t * 4) = *reinterpret_cast<float4*>(&s);
        __syncthreads();
        if (t < 64) {
            float4 a = *reinterpret_cast<float4*>(part + t * 4);
            float4 b2 = *reinterpret_cast<float4*>(part + (64 + t) * 4);
            float4 c = *reinterpret_cast<float4*>(part + (128 + t) * 4);
            float4 d = *reinterpret_cast<float4*>(part + (192 + t) * 4);
            float4 m = { (a.x + b2.x + c.x + d.x) * (1.f / 64.f),
                         (a.y + b2.y + c.y + d.y) * (1.f / 64.f),
                         (a.z + b2.z + c.z + d.z) * (1.f / 64.f),
                         (a.w + b2.w + c.w + d.w) * (1.f / 64.f) };
            *reinterpret_cast<float4*>(xmean + blk * 256 + t * 4) = m;
        }
    } else {
        float* tile = (float*)sm;                 // [64][65]
        int tb = blk - 196;
        const float* Wsrc; unsigned short* Wdst; int N, kt, nt;
        if (tb < 48) { Wsrc = Wqkv; Wdst = Wtq; N = 768; kt = tb / 12; nt = tb % 12; }
        else { tb -= 48; Wsrc = Wo; Wdst = Wto; N = 256; kt = tb / 4; nt = tb % 4; }
        const int k0 = kt * 64, n0 = nt * 64;
        const int r0 = t >> 6, c = t & 63;
        #pragma unroll
        for (int i = 0; i < 16; i++) {
            int r = i * 4 + r0;
            tile[r * 65 + c] = Wsrc[(size_t)(k0 + r) * N + n0 + c];
        }
        __syncthreads();
        #pragma unroll
        for (int i = 0; i < 16; i++) {
            int n = i * 4 + r0;
            Wdst[(size_t)(n0 + n) * 256 + k0 + c] = f2bf(tile[c * 65 + n]);
        }
    }
}

// ---------------------------------------------------------------------------
// K1: qkv GEMM (MFMA)  xb[12544,256] @ Wqkv[256,768] + bqkv -> qkv bf16
//     128x128 tile, BK=32, global_load_lds staging with source-side XOR:
//     LDS slot (row, c) holds global chunk e = c ^ ((row>>1)&3).
// ---------------------------------------------------------------------------
__global__ __launch_bounds__(256) void k_qkv_gemm(
    const unsigned short* __restrict__ A,   // xb [12544][256]
    const unsigned short* __restrict__ Bt,  // Wtq [768][256]
    const float* __restrict__ bias,
    unsigned short* __restrict__ O)
{
    __shared__ unsigned short As[128 * 32];   // 8 KB, unpadded (DMA layout)
    __shared__ unsigned short Bs[128 * 32];
    const int t = threadIdx.x;
    const int m0 = blockIdx.x * 128, n0 = blockIdx.y * 128;
    const int wave = t >> 6, lane = t & 63, quad = lane >> 4, lo = lane & 15;
    const int wm = wave & 1, wn = wave >> 1;
    const int sr = wave * 16 + (lane >> 2);   // staging row within 64-row half
    const int sc = lane & 3;                  // staging 16B chunk
    f32x4 acc[4][4];
    #pragma unroll
    for (int i = 0; i < 4; i++)
        #pragma unroll
        for (int j = 0; j < 4; j++) acc[i][j] = (f32x4){0.f, 0.f, 0.f, 0.f};

    for (int kt = 0; kt < 256; kt += 32) {
        __syncthreads();   // previous-iter fragment reads done
        #pragma unroll
        for (int j = 0; j < 2; j++) {
            int row = j * 64 + sr;
            int e = sc ^ ((row >> 1) & 3);
            load_lds16(A  + (size_t)(m0 + row) * 256 + kt + e * 8, &As[row * 32 + sc * 8]);
            load_lds16(Bt + (size_t)(n0 + row) * 256 + kt + e * 8, &Bs[row * 32 + sc * 8]);
        }
        __syncthreads();   // drain DMA (vmcnt) + make LDS visible
        bf16x8 af[4], bfr[4];
        #pragma unroll
        for (int mt = 0; mt < 4; mt++) {
            int row = wm * 64 + mt * 16 + lo;
            int c = quad ^ ((row >> 1) & 3);
            af[mt] = *reinterpret_cast<const bf16x8*>(&As[row * 32 + c * 8]);
        }
        #pragma unroll
        for (int nt = 0; nt < 4; nt++) {
            int col = wn * 64 + nt * 16 + lo;
            int c = quad ^ ((col >> 1) & 3);
            bfr[nt] = *reinterpret_cast<const bf16x8*>(&Bs[col * 32 + c * 8]);
        }
        #pragma unroll
        for (int mt = 0; mt < 4; mt++)
            #pragma unroll
            for (int nt = 0; nt < 4; nt++)
                acc[mt][nt] = __builtin_amdgcn_mfma_f32_16x16x32_bf16(
                    af[mt], bfr[nt], acc[mt][nt], 0, 0, 0);
    }
    float bv[4];
    #pragma unroll
    for (int nt = 0; nt < 4; nt++) bv[nt] = bias[n0 + wn * 64 + nt * 16 + lo];
    #pragma unroll
    for (int mt = 0; mt < 4; mt++)
        #pragma unroll
        for (int nt = 0; nt < 4; nt++) {
            int n = n0 + wn * 64 + nt * 16 + lo;
            #pragma unroll
            for (int r = 0; r < 4; r++) {
                int m = m0 + wm * 64 + mt * 16 + quad * 4 + r;
                O[m * 768 + n] = f2bf(acc[mt][nt][r] + bv[nt]);
            }
        }
}

// ---------------------------------------------------------------------------
// K3: winproj, split q/k across blockIdx.y (392 blocks)
// ---------------------------------------------------------------------------
__global__ __launch_bounds__(256) void k_winproj(
    const float* __restrict__ xmean,
    const float* __restrict__ W,
    const float* __restrict__ bias,
    float* __restrict__ qwin, float* __restrict__ kwin)
{
    __shared__ float xs[256];
    const int bp = blockIdx.x;
    const int half = blockIdx.y;          // 0 -> qwin, 1 -> kwin
    const int c = threadIdx.x;
    xs[c] = xmean[bp * 256 + c];
    __syncthreads();
    const int col = half * 256 + c;
    float a = 0.f;
    for (int k = 0; k < 256; k++) a += xs[k] * W[k * 768 + col];
    float* outp = half ? kwin : qwin;
    outp[bp * 256 + c] = a + bias[col];
}

// ---------------------------------------------------------------------------
// K4: routing logits + top-4, one block per (b, p)
// ---------------------------------------------------------------------------
__global__ __launch_bounds__(256) void k_route(
    const float* __restrict__ qwin, const float* __restrict__ kwin,
    int* __restrict__ ridx)
{
    __shared__ float part[49][4];
    __shared__ float lg[49];
    const int bp = blockIdx.x;
    const int b = bp / 49, p = bp % 49;
    const int t = threadIdx.x;
    if (t < 196) {
        int d = t >> 2, pr = t & 3;
        const float* qp = &qwin[(b * 49 + p) * 256];
        const float* kp = &kwin[(b * 49 + d) * 256];
        float a = 0.f;
        for (int ch = pr * 64; ch < pr * 64 + 64; ch++) a += qp[ch] * kp[ch];
        part[d][pr] = a;
    }
    __syncthreads();
    if (t < 49) lg[t] = (part[t][0] + part[t][1] + part[t][2] + part[t][3]);
    __syncthreads();
    if (t == 0) {
        unsigned long long used = 0ull;
        for (int sel = 0; sel < 4; sel++) {
            float best = -1e30f; int bi = 0;
            for (int qq = 0; qq < 49; qq++)
                if (!((used >> qq) & 1ull) && lg[qq] > best) { best = lg[qq]; bi = qq; }
            used |= (1ull << bi);
            ridx[bp * 4 + sel] = bi;
        }
    }
}

// ---------------------------------------------------------------------------
// K5: depthwise 5x5 LEPE conv on v channels -> bf16
// ---------------------------------------------------------------------------
__global__ __launch_bounds__(256) void k_lepe(
    const unsigned short* __restrict__ QKV,
    const float* __restrict__ lw, const float* __restrict__ lb,
    unsigned short* __restrict__ Olepe)
{
    __shared__ float lws[25 * 256];
    const int t = threadIdx.x;
    #pragma unroll
    for (int i = 0; i < 25; i++) lws[i * 256 + t] = lw[i * 256 + t];

    const int pl = t & 7;
    const int cg = t >> 3;
    const int c0 = cg * 8;
    const int gid = blockIdx.x * 8 + pl;
    const int b = gid / 3136, rem = gid % 3136;
    const int y = rem / 56, x = rem % 56;
    __syncthreads();

    float acc[8];
    {
        float4 b0 = *reinterpret_cast<const float4*>(lb + c0);
        float4 b1 = *reinterpret_cast<const float4*>(lb + c0 + 4);
        acc[0] = b0.x; acc[1] = b0.y; acc[2] = b0.z; acc[3] = b0.w;
        acc[4] = b1.x; acc[5] = b1.y; acc[6] = b1.z; acc[7] = b1.w;
    }
    #pragma unroll
    for (int ky = 0; ky < 5; ky++) {
        int yy = y + ky - 2;
        if (yy < 0 || yy >= 56) continue;
        #pragma unroll
        for (int kx = 0; kx < 5; kx++) {
            int xx = x + kx - 2;
            if (xx < 0 || xx >= 56) continue;
            bf16x8 v = *reinterpret_cast<const bf16x8*>(
                QKV + (((b * 56) + yy) * 56 + xx) * 768 + 512 + c0);
            const float* wrow = &lws[(ky * 5 + kx) * 256 + c0];
            float4 w0 = *reinterpret_cast<const float4*>(wrow);
            float4 w1 = *reinterpret_cast<const float4*>(wrow + 4);
            acc[0] += bf2f((unsigned short)v[0]) * w0.x;
            acc[1] += bf2f((unsigned short)v[1]) * w0.y;
            acc[2] += bf2f((unsigned short)v[2]) * w0.z;
            acc[3] += bf2f((unsigned short)v[3]) * w0.w;
            acc[4] += bf2f((unsigned short)v[4]) * w1.x;
            acc[5] += bf2f((unsigned short)v[5]) * w1.y;
            acc[6] += bf2f((unsigned short)v[6]) * w1.z;
            acc[7] += bf2f((unsigned short)v[7]) * w1.w;
        }
    }
    bf16x8 o;
    #pragma unroll
    for (int j = 0; j < 8; j++) o[j] = (short)f2bf(acc[j]);
    *reinterpret_cast<bf16x8*>(Olepe + (size_t)gid * 256 + c0) = o;
}

// ---------------------------------------------------------------------------
// K6: MFMA gathered window attention + fused "+lepe" epilogue -> Osum
// ---------------------------------------------------------------------------
__global__ __launch_bounds__(256) void k_attn(
    const unsigned short* __restrict__ QKV,
    const int* __restrict__ ridx,
    const unsigned short* __restrict__ Olepe,
    unsigned short* __restrict__ Osum)
{
    __shared__ __align__(16) unsigned char smem[50688];
    unsigned short* Vt = (unsigned short*)smem;                  // [32][264]
    unsigned short* Qs = (unsigned short*)(smem + 16896);        // [64][40]
    unsigned short* Ks = (unsigned short*)(smem + 22016);        // [256][40]
    unsigned short* Ps = (unsigned short*)(smem + 16896);        // 4 x [16][264]

    const int p = blockIdx.x, head = blockIdx.y, b = blockIdx.z;
    const int t = threadIdx.x;
    const int wi = p / 7, wj = p % 7;
    const int wave = t >> 6, lane = t & 63, quad = lane >> 4, lo = lane & 15;
    const int pix4 = t >> 2, c4 = t & 3;

    {
        int y = wi * 8 + (pix4 >> 3), x = wj * 8 + (pix4 & 7);
        const unsigned short* qp = QKV + (((b * 56) + y) * 56 + x) * 768 + head * 32 + c4 * 8;
        bf16x8 v = *reinterpret_cast<const bf16x8*>(qp);
        int sw = c4 ^ ((pix4 >> 3) & 3);
        *reinterpret_cast<bf16x8*>(&Qs[pix4 * 40 + sw * 8]) = v;
    }
    #pragma unroll
    for (int pass = 0; pass < 4; pass++) {
        int sel = ridx[(b * 49 + p) * 4 + pass];
        int si = sel / 7, sj = sel % 7;
        int y = si * 8 + (pix4 >> 3), x = sj * 8 + (pix4 & 7);
        const unsigned short* base = QKV + (((b * 56) + y) * 56 + x) * 768 + 256 + head * 32;
        bf16x8 kv = *reinterpret_cast<const bf16x8*>(base + c4 * 8);
        bf16x8 vv = *reinterpret_cast<const bf16x8*>(base + 256 + c4 * 8);
        int krow = pass * 64 + pix4;
        int sw = c4 ^ ((krow >> 3) & 3);
        *reinterpret_cast<bf16x8*>(&Ks[krow * 40 + sw * 8]) = kv;
        #pragma unroll
        for (int j = 0; j < 8; j++)
            Vt[(c4 * 8 + j) * 264 + krow] = (unsigned short)vv[j];
    }
    __syncthreads();

    f32x4 sc[16];
    {
        int row = wave * 16 + lo;
        bf16x8 af = *reinterpret_cast<const bf16x8*>(
            &Qs[row * 40 + ((quad ^ ((row >> 3) & 3)) * 8)]);
        f32x4 z = (f32x4){0.f, 0.f, 0.f, 0.f};
        #pragma unroll
        for (int nt = 0; nt < 16; nt++) {
            int key = nt * 16 + lo;
            bf16x8 bfr = *reinterpret_cast<const bf16x8*>(
                &Ks[key * 40 + ((quad ^ ((key >> 3) & 3)) * 8)]);
            sc[nt] = __builtin_amdgcn_mfma_f32_16x16x32_bf16(af, bfr, z, 0, 0, 0);
        }
    }
    float M[4] = {-1e30f, -1e30f, -1e30f, -1e30f};
    #pragma unroll
    for (int nt = 0; nt < 16; nt++)
        #pragma unroll
        for (int r = 0; r < 4; r++) M[r] = fmaxf(M[r], sc[nt][r] * 0.0625f);
    #pragma unroll
    for (int d = 1; d < 16; d <<= 1)
        #pragma unroll
        for (int r = 0; r < 4; r++) M[r] = fmaxf(M[r], __shfl_xor(M[r], d));
    float l[4] = {0.f, 0.f, 0.f, 0.f};
    #pragma unroll
    for (int nt = 0; nt < 16; nt++)
        #pragma unroll
        for (int r = 0; r < 4; r++) {
            float e = __expf(sc[nt][r] * 0.0625f - M[r]);
            sc[nt][r] = e;
            l[r] += e;
        }
    #pragma unroll
    for (int d = 1; d < 16; d <<= 1)
        #pragma unroll
        for (int r = 0; r < 4; r++) l[r] += __shfl_xor(l[r], d);

    __syncthreads();   // all waves done reading Qs/Ks -> Ps may overwrite

    unsigned short* myPs = Ps + wave * 16 * 264;
    #pragma unroll
    for (int nt = 0; nt < 16; nt++)
        #pragma unroll
        for (int r = 0; r < 4; r++)
            myPs[(quad * 4 + r) * 264 + nt * 16 + lo] = f2bf(sc[nt][r]);

    f32x4 o0 = (f32x4){0.f, 0.f, 0.f, 0.f}, o1 = o0;
    #pragma unroll
    for (int kt = 0; kt < 8; kt++) {
        bf16x8 pa = *reinterpret_cast<const bf16x8*>(
            &myPs[lo * 264 + kt * 32 + quad * 8]);
        bf16x8 vb0 = *reinterpret_cast<const bf16x8*>(
            &Vt[lo * 264 + kt * 32 + quad * 8]);
        bf16x8 vb1 = *reinterpret_cast<const bf16x8*>(
            &Vt[(16 + lo) * 264 + kt * 32 + quad * 8]);
        o0 = __builtin_amdgcn_mfma_f32_16x16x32_bf16(pa, vb0, o0, 0, 0, 0);
        o1 = __builtin_amdgcn_mfma_f32_16x16x32_bf16(pa, vb1, o1, 0, 0, 0);
    }
    #pragma unroll
    for (int r = 0; r < 4; r++) {
        int q = wave * 16 + quad * 4 + r;
        int y = wi * 8 + (q >> 3), x = wj * 8 + (q & 7);
        size_t base = (size_t)(((b * 56) + y) * 56 + x) * 256 + head * 32;
        const unsigned short* lp = Olepe + base;
        unsigned short* op = Osum + base;
        float inv = 1.0f / l[r];
        op[lo]      = f2bf(o0[r] * inv + bf2f(lp[lo]));
        op[16 + lo] = f2bf(o1[r] * inv + bf2f(lp[16 + lo]));
    }
}

// ---------------------------------------------------------------------------
// K7: out proj (MFMA): Osum[12544,256] @ Wo[256,256] + bo -> fp32 out
//     global_load_lds staging, same XOR scheme as k_qkv_gemm.
// ---------------------------------------------------------------------------
__global__ __launch_bounds__(256) void k_proj(
    const unsigned short* __restrict__ A,
    const unsigned short* __restrict__ Bt,   // Wto [256][256]
    const float* __restrict__ bias,
    float* __restrict__ O)
{
    __shared__ unsigned short As[128 * 32];
    __shared__ unsigned short Bs[64 * 32];
    const int t = threadIdx.x;
    const int m0 = blockIdx.x * 128, n0 = blockIdx.y * 64;
    const int wave = t >> 6, lane = t & 63, quad = lane >> 4, lo = lane & 15;
    const int sr = wave * 16 + (lane >> 2);
    const int sc = lane & 3;
    f32x4 acc[2][4];
    #pragma unroll
    for (int i = 0; i < 2; i++)
        #pragma unroll
        for (int j = 0; j < 4; j++) acc[i][j] = (f32x4){0.f, 0.f, 0.f, 0.f};

    for (int kt = 0; kt < 256; kt += 32) {
        __syncthreads();
        #pragma unroll
        for (int j = 0; j < 2; j++) {
            int row = j * 64 + sr;
            int e = sc ^ ((row >> 1) & 3);
            load_lds16(A + (size_t)(m0 + row) * 256 + kt + e * 8, &As[row * 32 + sc * 8]);
        }
        {
            int e = sc ^ ((sr >> 1) & 3);
            load_lds16(Bt + (size_t)(n0 + sr) * 256 + kt + e * 8, &Bs[sr * 32 + sc * 8]);
        }
        __syncthreads();
        bf16x8 af[2], bfr[4];
        #pragma unroll
        for (int mt = 0; mt < 2; mt++) {
            int row = wave * 32 + mt * 16 + lo;
            int c = quad ^ ((row >> 1) & 3);
            af[mt] = *reinterpret_cast<const bf16x8*>(&As[row * 32 + c * 8]);
        }
        #pragma unroll
        for (int nt = 0; nt < 4; nt++) {
            int col = nt * 16 + lo;
            int c = quad ^ ((col >> 1) & 3);
            bfr[nt] = *reinterpret_cast<const bf16x8*>(&Bs[col * 32 + c * 8]);
        }
        #pragma unroll
        for (int mt = 0; mt < 2; mt++)
            #pragma unroll
            for (int nt = 0; nt < 4; nt++)
                acc[mt][nt] = __builtin_amdgcn_mfma_f32_16x16x32_bf16(
                    af[mt], bfr[nt], acc[mt][nt], 0, 0, 0);
    }
    float bv[4];
    #pragma unroll
    for (int nt = 0; nt < 4; nt++) bv[nt] = bias[n0 + nt * 16 + lo];
    #pragma unroll
    for (int mt = 0; mt < 2; mt++)
        #pragma unroll
        for (int nt = 0; nt < 4; nt++) {
            int n = n0 + nt * 16 + lo;
            #pragma unroll
            for (int r = 0; r < 4; r++) {
                int m = m0 + wave * 32 + mt * 16 + quad * 4 + r;
                O[m * 256 + n] = acc[mt][nt][r] + bv[nt];
            }
        }
}

// ---------------------------------------------------------------------------
extern "C" void kernel_launch(void* const* d_in, const int* in_sizes, int n_in,
                              void* d_out, int out_size, void* d_ws, size_t ws_size,
                              hipStream_t stream)
{
    const float* x    = (const float*)d_in[0];
    const float* Wqkv = (const float*)d_in[1];
    const float* bqkv = (const float*)d_in[2];
    const float* Wo   = (const float*)d_in[3];
    const float* bo   = (const float*)d_in[4];
    const float* lw   = (const float*)d_in[5];
    const float* lb   = (const float*)d_in[6];
    float* out = (float*)d_out;

    char* ws = (char*)d_ws;
    size_t off = 0;
    unsigned short* qkv   = (unsigned short*)(ws + off); off += (size_t)NPIX * 768 * 2;
    unsigned short* xb    = (unsigned short*)(ws + off); off += (size_t)NPIX * 256 * 2;
    unsigned short* Wtq   = (unsigned short*)(ws + off); off += 768 * 256 * 2;
    unsigned short* Wto   = (unsigned short*)(ws + off); off += 256 * 256 * 2;
    unsigned short* Osum  = (unsigned short*)(ws + off); off += (size_t)NPIX * 256 * 2;
    unsigned short* Olepe = (unsigned short*)(ws + off); off += (size_t)NPIX * 256 * 2;
    float* xmean = (float*)(ws + off); off += 196 * 256 * 4;
    float* qwin  = (float*)(ws + off); off += 196 * 256 * 4;
    float* kwin  = (float*)(ws + off); off += 196 * 256 * 4;
    int*   ridx  = (int*)(ws + off);   off += 196 * 4 * 4;

    k_prep    <<<dim3(260),      256, 0, stream>>>(x, xb, xmean, Wqkv, Wo, Wtq, Wto);
    k_qkv_gemm<<<dim3(98, 6),    256, 0, stream>>>(xb, Wtq, bqkv, qkv);
    k_winproj <<<dim3(196, 2),   256, 0, stream>>>(xmean, Wqkv, bqkv, qwin, kwin);
    k_route   <<<dim3(196),      256, 0, stream>>>(qwin, kwin, ridx);
    k_lepe    <<<dim3(1568),     256, 0, stream>>>(qkv, lw, lb, Olepe);
    k_attn    <<<dim3(49, 8, 4), 256, 0, stream>>>(qkv, ridx, Olepe, Osum);
    k_proj    <<<dim3(98, 4),    256, 0, stream>>>(Osum, Wto, bo, out);
}

// Round 8
// 153.203 us; speedup vs baseline: 3.8088x; 1.0981x over previous
//
#include <hip/hip_runtime.h>
#include <hip/hip_bf16.h>

// B=4, H=W=56, C=256, 7x7 windows of 8x8, 8 heads x 32, top-4.
// Inputs fp32; d_out fp32. Intermediates bf16; MFMA bf16 w/ fp32 accum.
// 5-launch pipeline: prep -> [qkv_gemm|winproj] -> [route|lepe] -> attn -> proj
#define NPIX 12544   // B*56*56

typedef short bf16x8 __attribute__((ext_vector_type(8)));
typedef float f32x4  __attribute__((ext_vector_type(4)));

__device__ __forceinline__ float bf2f(unsigned short u) {
    unsigned int x = ((unsigned int)u) << 16;
    float f; __builtin_memcpy(&f, &x, sizeof(f)); return f;
}
__device__ __forceinline__ unsigned short f2bf(float f) {
    __hip_bfloat16 h = __float2bfloat16(f);
    unsigned short u; __builtin_memcpy(&u, &h, 2); return u;
}
// async global->LDS DMA, 16B per lane; LDS dest is wave-uniform base + lane*16
__device__ __forceinline__ void load_lds16(const unsigned short* g, unsigned short* l) {
    __builtin_amdgcn_global_load_lds(
        (const __attribute__((address_space(1))) unsigned int*)g,
        (__attribute__((address_space(3))) unsigned int*)l,
        16, 0, 0);
}

// ---------------------------------------------------------------------------
// K0: fused prep.
//   blocks 0..391   : x -> bf16 + per-window mean (2 blocks/window, 128 ch each)
//   blocks 392..439 : Wqkv^T tiles (64x64 LDS transpose)
//   blocks 440..455 : Wo^T tiles
// ---------------------------------------------------------------------------
__global__ __launch_bounds__(256) void k_prep(
    const float* __restrict__ X, unsigned short* __restrict__ Xb,
    float* __restrict__ xmean,
    const float* __restrict__ Wqkv, const float* __restrict__ Wo,
    unsigned short* __restrict__ Wtq, unsigned short* __restrict__ Wto)
{
    __shared__ __align__(16) unsigned char sm[64 * 65 * 4];   // 16.6 KB union
    const int t = threadIdx.x;
    const int blk = blockIdx.x;
    if (blk < 392) {
        float* part = (float*)sm;                 // [8 ps][32 cg][4]
        const int w = blk >> 1, hc = blk & 1;
        const int b = w / 49, p = w % 49;
        const int wi = p / 7, wj = p % 7;
        const int ch0 = hc * 128;
        const int ps = t >> 5, cg = t & 31;
        float4 s = {0.f, 0.f, 0.f, 0.f};
        #pragma unroll
        for (int i = 0; i < 8; i++) {
            int pp = ps * 8 + i;
            int y = wi * 8 + (pp >> 3), x = wj * 8 + (pp & 7);
            int idx = (((b * 56) + y) * 56 + x) * 256 + ch0 + cg * 4;
            float4 v = *reinterpret_cast<const float4*>(X + idx);
            s.x += v.x; s.y += v.y; s.z += v.z; s.w += v.w;
            ushort4 o = { f2bf(v.x), f2bf(v.y), f2bf(v.z), f2bf(v.w) };
            *reinterpret_cast<ushort4*>(Xb + idx) = o;
        }
        *reinterpret_cast<float4*>(part + t * 4) = *reinterpret_cast<float4*>(&s);
        __syncthreads();
        if (t < 32) {
            float4 m = {0.f, 0.f, 0.f, 0.f};
            #pragma unroll
            for (int ps2 = 0; ps2 < 8; ps2++) {
                float4 v = *reinterpret_cast<float4*>(part + (ps2 * 32 + t) * 4);
                m.x += v.x; m.y += v.y; m.z += v.z; m.w += v.w;
            }
            m.x *= (1.f / 64.f); m.y *= (1.f / 64.f);
            m.z *= (1.f / 64.f); m.w *= (1.f / 64.f);
            *reinterpret_cast<float4*>(xmean + w * 256 + ch0 + t * 4) = m;
        }
    } else {
        float* tile = (float*)sm;                 // [64][65]
        int tb = blk - 392;
        const float* Wsrc; unsigned short* Wdst; int N, kt, nt;
        if (tb < 48) { Wsrc = Wqkv; Wdst = Wtq; N = 768; kt = tb / 12; nt = tb % 12; }
        else { tb -= 48; Wsrc = Wo; Wdst = Wto; N = 256; kt = tb / 4; nt = tb % 4; }
        const int k0 = kt * 64, n0 = nt * 64;
        const int r0 = t >> 6, c = t & 63;
        #pragma unroll
        for (int i = 0; i < 16; i++) {
            int r = i * 4 + r0;
            tile[r * 65 + c] = Wsrc[(size_t)(k0 + r) * N + n0 + c];
        }
        __syncthreads();
        #pragma unroll
        for (int i = 0; i < 16; i++) {
            int n = i * 4 + r0;
            Wdst[(size_t)(n0 + n) * 256 + k0 + c] = f2bf(tile[c * 65 + n]);
        }
    }
}

// ---------------------------------------------------------------------------
// K1: merged launch — qkv GEMM (blocks 0..587) | winproj (blocks 588..979)
// ---------------------------------------------------------------------------
__global__ __launch_bounds__(256) void k_main1(
    const unsigned short* __restrict__ A,   // xb [12544][256]
    const unsigned short* __restrict__ Bt,  // Wtq [768][256]
    const float* __restrict__ bias,         // bqkv [768]
    unsigned short* __restrict__ O,         // qkv bf16
    const float* __restrict__ xmean,
    const float* __restrict__ Wqkv,         // fp32 [256][768]
    float* __restrict__ qwin, float* __restrict__ kwin)
{
    __shared__ __align__(16) unsigned char sm1[16384];
    const int t = threadIdx.x;
    const int blk = blockIdx.x;
    if (blk < 588) {
        unsigned short* As = (unsigned short*)sm1;          // [128*32]
        unsigned short* Bs = (unsigned short*)(sm1 + 8192); // [128*32]
        const int m0 = (blk % 98) * 128, n0 = (blk / 98) * 128;
        const int wave = t >> 6, lane = t & 63, quad = lane >> 4, lo = lane & 15;
        const int wm = wave & 1, wn = wave >> 1;
        const int sr = wave * 16 + (lane >> 2);
        const int sc = lane & 3;
        f32x4 acc[4][4];
        #pragma unroll
        for (int i = 0; i < 4; i++)
            #pragma unroll
            for (int j = 0; j < 4; j++) acc[i][j] = (f32x4){0.f, 0.f, 0.f, 0.f};

        for (int kt = 0; kt < 256; kt += 32) {
            __syncthreads();
            #pragma unroll
            for (int j = 0; j < 2; j++) {
                int row = j * 64 + sr;
                int e = sc ^ ((row >> 1) & 3);
                load_lds16(A  + (size_t)(m0 + row) * 256 + kt + e * 8, &As[row * 32 + sc * 8]);
                load_lds16(Bt + (size_t)(n0 + row) * 256 + kt + e * 8, &Bs[row * 32 + sc * 8]);
            }
            __syncthreads();
            bf16x8 af[4], bfr[4];
            #pragma unroll
            for (int mt = 0; mt < 4; mt++) {
                int row = wm * 64 + mt * 16 + lo;
                int c = quad ^ ((row >> 1) & 3);
                af[mt] = *reinterpret_cast<const bf16x8*>(&As[row * 32 + c * 8]);
            }
            #pragma unroll
            for (int nt = 0; nt < 4; nt++) {
                int col = wn * 64 + nt * 16 + lo;
                int c = quad ^ ((col >> 1) & 3);
                bfr[nt] = *reinterpret_cast<const bf16x8*>(&Bs[col * 32 + c * 8]);
            }
            #pragma unroll
            for (int mt = 0; mt < 4; mt++)
                #pragma unroll
                for (int nt = 0; nt < 4; nt++)
                    acc[mt][nt] = __builtin_amdgcn_mfma_f32_16x16x32_bf16(
                        af[mt], bfr[nt], acc[mt][nt], 0, 0, 0);
        }
        float bv[4];
        #pragma unroll
        for (int nt = 0; nt < 4; nt++) bv[nt] = bias[n0 + wn * 64 + nt * 16 + lo];
        #pragma unroll
        for (int mt = 0; mt < 4; mt++)
            #pragma unroll
            for (int nt = 0; nt < 4; nt++) {
                int n = n0 + wn * 64 + nt * 16 + lo;
                #pragma unroll
                for (int r = 0; r < 4; r++) {
                    int m = m0 + wm * 64 + mt * 16 + quad * 4 + r;
                    O[m * 768 + n] = f2bf(acc[mt][nt][r] + bv[nt]);
                }
            }
    } else {
        float* xs = (float*)sm1;                  // [256]
        const int u = blk - 588;
        const int bp = u % 196;
        const int half = u / 196;                 // 0 -> qwin, 1 -> kwin
        const int c = t;
        xs[c] = xmean[bp * 256 + c];
        __syncthreads();
        const int col = half * 256 + c;
        float a = 0.f;
        for (int k = 0; k < 256; k++) a += xs[k] * Wqkv[k * 768 + col];
        float* outp = half ? kwin : qwin;
        outp[bp * 256 + c] = a + bias[col];
    }
}

// ---------------------------------------------------------------------------
// K2: merged launch — route (blocks 0..195) | lepe (blocks 196..1763)
// ---------------------------------------------------------------------------
__global__ __launch_bounds__(256) void k_main2(
    const float* __restrict__ qwin, const float* __restrict__ kwin,
    int* __restrict__ ridx,
    const unsigned short* __restrict__ QKV,
    const float* __restrict__ lw, const float* __restrict__ lb,
    unsigned short* __restrict__ Olepe)
{
    __shared__ __align__(16) unsigned char sm2[25600];
    const int t = threadIdx.x;
    const int blk = blockIdx.x;
    if (blk < 196) {
        float* part = (float*)sm2;                // [49][4]
        float* lg   = (float*)(sm2 + 49 * 4 * 4); // [49]
        const int b = blk / 49, p = blk % 49;
        if (t < 196) {
            int d = t >> 2, pr = t & 3;
            const float* qp = &qwin[(b * 49 + p) * 256];
            const float* kp = &kwin[(b * 49 + d) * 256];
            float a = 0.f;
            for (int ch = pr * 64; ch < pr * 64 + 64; ch++) a += qp[ch] * kp[ch];
            part[d * 4 + pr] = a;
        }
        __syncthreads();
        if (t < 49) lg[t] = part[t * 4 + 0] + part[t * 4 + 1] + part[t * 4 + 2] + part[t * 4 + 3];
        __syncthreads();
        if (t == 0) {
            unsigned long long used = 0ull;
            for (int sel = 0; sel < 4; sel++) {
                float best = -1e30f; int bi = 0;
                for (int qq = 0; qq < 49; qq++)
                    if (!((used >> qq) & 1ull) && lg[qq] > best) { best = lg[qq]; bi = qq; }
                used |= (1ull << bi);
                ridx[blk * 4 + sel] = bi;
            }
        }
    } else {
        float* lws = (float*)sm2;                 // [25*256]
        #pragma unroll
        for (int i = 0; i < 25; i++) lws[i * 256 + t] = lw[i * 256 + t];

        const int pl = t & 7;
        const int cg = t >> 3;
        const int c0 = cg * 8;
        const int gid = (blk - 196) * 8 + pl;
        const int b = gid / 3136, rem = gid % 3136;
        const int y = rem / 56, x = rem % 56;
        __syncthreads();

        float acc[8];
        {
            float4 b0 = *reinterpret_cast<const float4*>(lb + c0);
            float4 b1 = *reinterpret_cast<const float4*>(lb + c0 + 4);
            acc[0] = b0.x; acc[1] = b0.y; acc[2] = b0.z; acc[3] = b0.w;
            acc[4] = b1.x; acc[5] = b1.y; acc[6] = b1.z; acc[7] = b1.w;
        }
        #pragma unroll
        for (int ky = 0; ky < 5; ky++) {
            int yy = y + ky - 2;
            if (yy < 0 || yy >= 56) continue;
            #pragma unroll
            for (int kx = 0; kx < 5; kx++) {
                int xx = x + kx - 2;
                if (xx < 0 || xx >= 56) continue;
                bf16x8 v = *reinterpret_cast<const bf16x8*>(
                    QKV + (((b * 56) + yy) * 56 + xx) * 768 + 512 + c0);
                const float* wrow = &lws[(ky * 5 + kx) * 256 + c0];
                float4 w0 = *reinterpret_cast<const float4*>(wrow);
                float4 w1 = *reinterpret_cast<const float4*>(wrow + 4);
                acc[0] += bf2f((unsigned short)v[0]) * w0.x;
                acc[1] += bf2f((unsigned short)v[1]) * w0.y;
                acc[2] += bf2f((unsigned short)v[2]) * w0.z;
                acc[3] += bf2f((unsigned short)v[3]) * w0.w;
                acc[4] += bf2f((unsigned short)v[4]) * w1.x;
                acc[5] += bf2f((unsigned short)v[5]) * w1.y;
                acc[6] += bf2f((unsigned short)v[6]) * w1.z;
                acc[7] += bf2f((unsigned short)v[7]) * w1.w;
            }
        }
        bf16x8 o;
        #pragma unroll
        for (int j = 0; j < 8; j++) o[j] = (short)f2bf(acc[j]);
        *reinterpret_cast<bf16x8*>(Olepe + (size_t)gid * 256 + c0) = o;
    }
}

// ---------------------------------------------------------------------------
// K6: MFMA gathered window attention + fused "+lepe" epilogue -> Osum
// ---------------------------------------------------------------------------
__global__ __launch_bounds__(256) void k_attn(
    const unsigned short* __restrict__ QKV,
    const int* __restrict__ ridx,
    const unsigned short* __restrict__ Olepe,
    unsigned short* __restrict__ Osum)
{
    __shared__ __align__(16) unsigned char smem[50688];
    unsigned short* Vt = (unsigned short*)smem;                  // [32][264]
    unsigned short* Qs = (unsigned short*)(smem + 16896);        // [64][40]
    unsigned short* Ks = (unsigned short*)(smem + 22016);        // [256][40]
    unsigned short* Ps = (unsigned short*)(smem + 16896);        // 4 x [16][264]

    const int p = blockIdx.x, head = blockIdx.y, b = blockIdx.z;
    const int t = threadIdx.x;
    const int wi = p / 7, wj = p % 7;
    const int wave = t >> 6, lane = t & 63, quad = lane >> 4, lo = lane & 15;
    const int pix4 = t >> 2, c4 = t & 3;

    {
        int y = wi * 8 + (pix4 >> 3), x = wj * 8 + (pix4 & 7);
        const unsigned short* qp = QKV + (((b * 56) + y) * 56 + x) * 768 + head * 32 + c4 * 8;
        bf16x8 v = *reinterpret_cast<const bf16x8*>(qp);
        int sw = c4 ^ ((pix4 >> 3) & 3);
        *reinterpret_cast<bf16x8*>(&Qs[pix4 * 40 + sw * 8]) = v;
    }
    #pragma unroll
    for (int pass = 0; pass < 4; pass++) {
        int sel = ridx[(b * 49 + p) * 4 + pass];
        int si = sel / 7, sj = sel % 7;
        int y = si * 8 + (pix4 >> 3), x = sj * 8 + (pix4 & 7);
        const unsigned short* base = QKV + (((b * 56) + y) * 56 + x) * 768 + 256 + head * 32;
        bf16x8 kv = *reinterpret_cast<const bf16x8*>(base + c4 * 8);
        bf16x8 vv = *reinterpret_cast<const bf16x8*>(base + 256 + c4 * 8);
        int krow = pass * 64 + pix4;
        int sw = c4 ^ ((krow >> 3) & 3);
        *reinterpret_cast<bf16x8*>(&Ks[krow * 40 + sw * 8]) = kv;
        #pragma unroll
        for (int j = 0; j < 8; j++)
            Vt[(c4 * 8 + j) * 264 + krow] = (unsigned short)vv[j];
    }
    __syncthreads();

    f32x4 sc[16];
    {
        int row = wave * 16 + lo;
        bf16x8 af = *reinterpret_cast<const bf16x8*>(
            &Qs[row * 40 + ((quad ^ ((row >> 3) & 3)) * 8)]);
        f32x4 z = (f32x4){0.f, 0.f, 0.f, 0.f};
        #pragma unroll
        for (int nt = 0; nt < 16; nt++) {
            int key = nt * 16 + lo;
            bf16x8 bfr = *reinterpret_cast<const bf16x8*>(
                &Ks[key * 40 + ((quad ^ ((key >> 3) & 3)) * 8)]);
            sc[nt] = __builtin_amdgcn_mfma_f32_16x16x32_bf16(af, bfr, z, 0, 0, 0);
        }
    }
    float M[4] = {-1e30f, -1e30f, -1e30f, -1e30f};
    #pragma unroll
    for (int nt = 0; nt < 16; nt++)
        #pragma unroll
        for (int r = 0; r < 4; r++) M[r] = fmaxf(M[r], sc[nt][r] * 0.0625f);
    #pragma unroll
    for (int d = 1; d < 16; d <<= 1)
        #pragma unroll
        for (int r = 0; r < 4; r++) M[r] = fmaxf(M[r], __shfl_xor(M[r], d));
    float l[4] = {0.f, 0.f, 0.f, 0.f};
    #pragma unroll
    for (int nt = 0; nt < 16; nt++)
        #pragma unroll
        for (int r = 0; r < 4; r++) {
            float e = __expf(sc[nt][r] * 0.0625f - M[r]);
            sc[nt][r] = e;
            l[r] += e;
        }
    #pragma unroll
    for (int d = 1; d < 16; d <<= 1)
        #pragma unroll
        for (int r = 0; r < 4; r++) l[r] += __shfl_xor(l[r], d);

    __syncthreads();   // all waves done reading Qs/Ks -> Ps may overwrite

    unsigned short* myPs = Ps + wave * 16 * 264;
    #pragma unroll
    for (int nt = 0; nt < 16; nt++)
        #pragma unroll
        for (int r = 0; r < 4; r++)
            myPs[(quad * 4 + r) * 264 + nt * 16 + lo] = f2bf(sc[nt][r]);

    f32x4 o0 = (f32x4){0.f, 0.f, 0.f, 0.f}, o1 = o0;
    #pragma unroll
    for (int kt = 0; kt < 8; kt++) {
        bf16x8 pa = *reinterpret_cast<const bf16x8*>(
            &myPs[lo * 264 + kt * 32 + quad * 8]);
        bf16x8 vb0 = *reinterpret_cast<const bf16x8*>(
            &Vt[lo * 264 + kt * 32 + quad * 8]);
        bf16x8 vb1 = *reinterpret_cast<const bf16x8*>(
            &Vt[(16 + lo) * 264 + kt * 32 + quad * 8]);
        o0 = __builtin_amdgcn_mfma_f32_16x16x32_bf16(pa, vb0, o0, 0, 0, 0);
        o1 = __builtin_amdgcn_mfma_f32_16x16x32_bf16(pa, vb1, o1, 0, 0, 0);
    }
    #pragma unroll
    for (int r = 0; r < 4; r++) {
        int q = wave * 16 + quad * 4 + r;
        int y = wi * 8 + (q >> 3), x = wj * 8 + (q & 7);
        size_t base = (size_t)(((b * 56) + y) * 56 + x) * 256 + head * 32;
        const unsigned short* lp = Olepe + base;
        unsigned short* op = Osum + base;
        float inv = 1.0f / l[r];
        op[lo]      = f2bf(o0[r] * inv + bf2f(lp[lo]));
        op[16 + lo] = f2bf(o1[r] * inv + bf2f(lp[16 + lo]));
    }
}

// ---------------------------------------------------------------------------
// K7: out proj (MFMA): Osum[12544,256] @ Wo[256,256] + bo -> fp32 out
// ---------------------------------------------------------------------------
__global__ __launch_bounds__(256) void k_proj(
    const unsigned short* __restrict__ A,
    const unsigned short* __restrict__ Bt,   // Wto [256][256]
    const float* __restrict__ bias,
    float* __restrict__ O)
{
    __shared__ unsigned short As[128 * 32];
    __shared__ unsigned short Bs[64 * 32];
    const int t = threadIdx.x;
    const int m0 = blockIdx.x * 128, n0 = blockIdx.y * 64;
    const int wave = t >> 6, lane = t & 63, quad = lane >> 4, lo = lane & 15;
    const int sr = wave * 16 + (lane >> 2);
    const int sc = lane & 3;
    f32x4 acc[2][4];
    #pragma unroll
    for (int i = 0; i < 2; i++)
        #pragma unroll
        for (int j = 0; j < 4; j++) acc[i][j] = (f32x4){0.f, 0.f, 0.f, 0.f};

    for (int kt = 0; kt < 256; kt += 32) {
        __syncthreads();
        #pragma unroll
        for (int j = 0; j < 2; j++) {
            int row = j * 64 + sr;
            int e = sc ^ ((row >> 1) & 3);
            load_lds16(A + (size_t)(m0 + row) * 256 + kt + e * 8, &As[row * 32 + sc * 8]);
        }
        {
            int e = sc ^ ((sr >> 1) & 3);
            load_lds16(Bt + (size_t)(n0 + sr) * 256 + kt + e * 8, &Bs[sr * 32 + sc * 8]);
        }
        __syncthreads();
        bf16x8 af[2], bfr[4];
        #pragma unroll
        for (int mt = 0; mt < 2; mt++) {
            int row = wave * 32 + mt * 16 + lo;
            int c = quad ^ ((row >> 1) & 3);
            af[mt] = *reinterpret_cast<const bf16x8*>(&As[row * 32 + c * 8]);
        }
        #pragma unroll
        for (int nt = 0; nt < 4; nt++) {
            int col = nt * 16 + lo;
            int c = quad ^ ((col >> 1) & 3);
            bfr[nt] = *reinterpret_cast<const bf16x8*>(&Bs[col * 32 + c * 8]);
        }
        #pragma unroll
        for (int mt = 0; mt < 2; mt++)
            #pragma unroll
            for (int nt = 0; nt < 4; nt++)
                acc[mt][nt] = __builtin_amdgcn_mfma_f32_16x16x32_bf16(
                    af[mt], bfr[nt], acc[mt][nt], 0, 0, 0);
    }
    float bv[4];
    #pragma unroll
    for (int nt = 0; nt < 4; nt++) bv[nt] = bias[n0 + nt * 16 + lo];
    #pragma unroll
    for (int mt = 0; mt < 2; mt++)
        #pragma unroll
        for (int nt = 0; nt < 4; nt++) {
            int n = n0 + nt * 16 + lo;
            #pragma unroll
            for (int r = 0; r < 4; r++) {
                int m = m0 + wave * 32 + mt * 16 + quad * 4 + r;
                O[m * 256 + n] = acc[mt][nt][r] + bv[nt];
            }
        }
}

// ---------------------------------------------------------------------------
extern "C" void kernel_launch(void* const* d_in, const int* in_sizes, int n_in,
                              void* d_out, int out_size, void* d_ws, size_t ws_size,
                              hipStream_t stream)
{
    const float* x    = (const float*)d_in[0];
    const float* Wqkv = (const float*)d_in[1];
    const float* bqkv = (const float*)d_in[2];
    const float* Wo   = (const float*)d_in[3];
    const float* bo   = (const float*)d_in[4];
    const float* lw   = (const float*)d_in[5];
    const float* lb   = (const float*)d_in[6];
    float* out = (float*)d_out;

    char* ws = (char*)d_ws;
    size_t off = 0;
    unsigned short* qkv   = (unsigned short*)(ws + off); off += (size_t)NPIX * 768 * 2;
    unsigned short* xb    = (unsigned short*)(ws + off); off += (size_t)NPIX * 256 * 2;
    unsigned short* Wtq   = (unsigned short*)(ws + off); off += 768 * 256 * 2;
    unsigned short* Wto   = (unsigned short*)(ws + off); off += 256 * 256 * 2;
    unsigned short* Osum  = (unsigned short*)(ws + off); off += (size_t)NPIX * 256 * 2;
    unsigned short* Olepe = (unsigned short*)(ws + off); off += (size_t)NPIX * 256 * 2;
    float* xmean = (float*)(ws + off); off += 196 * 256 * 4;
    float* qwin  = (float*)(ws + off); off += 196 * 256 * 4;
    float* kwin  = (float*)(ws + off); off += 196 * 256 * 4;
    int*   ridx  = (int*)(ws + off);   off += 196 * 4 * 4;

    k_prep <<<dim3(456),      256, 0, stream>>>(x, xb, xmean, Wqkv, Wo, Wtq, Wto);
    k_main1<<<dim3(980),      256, 0, stream>>>(xb, Wtq, bqkv, qkv, xmean, Wqkv, qwin, kwin);
    k_main2<<<dim3(1764),     256, 0, stream>>>(qwin, kwin, ridx, qkv, lw, lb, Olepe);
    k_attn <<<dim3(49, 8, 4), 256, 0, stream>>>(qkv, ridx, Olepe, Osum);
    k_proj <<<dim3(98, 4),    256, 0, stream>>>(Osum, Wto, bo, out);
}